// Round 1
// baseline (10534.707 us; speedup 1.0000x reference)
//
#include <hip/hip_runtime.h>
#include <math.h>

// Problem constants
#define Bb   4
#define Ss   1024
#define Ee   1024
#define Nn   16
#define Hh   64
#define Ff   4096
#define Rr   2048
#define NHh  1024   // N*H
#define BSs  4096   // B*S

// ---------------------------------------------------------------------------
// Generic fp32 GEMM: C[M,N] = A[M,K] @ B[K,N] (+ bias) (+ relu)
// Tile: 128(M) x 64(N) x 16(K), 256 threads, 8x4 micro-tile per thread.
// All dims in this problem are multiples of the tile sizes -> no bounds checks.
// ---------------------------------------------------------------------------
template<int BIAS, int RELU>
__global__ __launch_bounds__(256) void gemm_f32(
    const float* __restrict__ A, const float* __restrict__ Bm,
    const float* __restrict__ bias, float* __restrict__ C,
    int M, int N, int K)
{
    __shared__ float As[16][128];   // [k][m]
    __shared__ float Bs[16][64];    // [k][n]

    const int tid  = threadIdx.x;
    const int row0 = blockIdx.y * 128;
    const int col0 = blockIdx.x * 64;
    const int tm   = tid >> 4;      // 0..15 -> 8 rows each
    const int tn   = tid & 15;      // 0..15 -> 4 cols each

    float acc[8][4] = {{0.f}};

    for (int k0 = 0; k0 < K; k0 += 16) {
        // Stage A tile (128 rows x 16 k): 2 threads per row, 8 floats each.
        {
            const int m  = tid >> 1;
            const int kk = (tid & 1) * 8;
            const float* ap = A + (size_t)(row0 + m) * K + (k0 + kk);
            const float4 a0 = *reinterpret_cast<const float4*>(ap);
            const float4 a1 = *reinterpret_cast<const float4*>(ap + 4);
            As[kk+0][m] = a0.x; As[kk+1][m] = a0.y;
            As[kk+2][m] = a0.z; As[kk+3][m] = a0.w;
            As[kk+4][m] = a1.x; As[kk+5][m] = a1.y;
            As[kk+6][m] = a1.z; As[kk+7][m] = a1.w;
        }
        // Stage B tile (16 k x 64 n): one float4 per thread.
        {
            const int kk = tid >> 4;
            const int nn = (tid & 15) * 4;
            *reinterpret_cast<float4*>(&Bs[kk][nn]) =
                *reinterpret_cast<const float4*>(Bm + (size_t)(k0 + kk) * N + col0 + nn);
        }
        __syncthreads();

        #pragma unroll
        for (int kk = 0; kk < 16; ++kk) {
            float a[8], bv[4];
            *reinterpret_cast<float4*>(&a[0]) =
                *reinterpret_cast<const float4*>(&As[kk][tm * 8]);
            *reinterpret_cast<float4*>(&a[4]) =
                *reinterpret_cast<const float4*>(&As[kk][tm * 8 + 4]);
            *reinterpret_cast<float4*>(&bv[0]) =
                *reinterpret_cast<const float4*>(&Bs[kk][tn * 4]);
            #pragma unroll
            for (int i = 0; i < 8; ++i)
                #pragma unroll
                for (int j = 0; j < 4; ++j)
                    acc[i][j] = fmaf(a[i], bv[j], acc[i][j]);
        }
        __syncthreads();
    }

    float bv[4] = {0.f, 0.f, 0.f, 0.f};
    if (BIAS) {
        const float4 bb = *reinterpret_cast<const float4*>(&bias[col0 + tn * 4]);
        bv[0] = bb.x; bv[1] = bb.y; bv[2] = bb.z; bv[3] = bb.w;
    }
    #pragma unroll
    for (int i = 0; i < 8; ++i) {
        const int row = row0 + tm * 8 + i;
        float4 o;
        float t0 = acc[i][0] + bv[0];
        float t1 = acc[i][1] + bv[1];
        float t2 = acc[i][2] + bv[2];
        float t3 = acc[i][3] + bv[3];
        if (RELU) {
            t0 = fmaxf(t0, 0.f); t1 = fmaxf(t1, 0.f);
            t2 = fmaxf(t2, 0.f); t3 = fmaxf(t3, 0.f);
        }
        o.x = t0; o.y = t1; o.z = t2; o.w = t3;
        *reinterpret_cast<float4*>(C + (size_t)row * N + col0 + tn * 4) = o;
    }
}

// ---------------------------------------------------------------------------
// Fused attention: one block per (i, n, b) query row.
// scores[j] = k[b,j,n,:].(q_i+cb) + r[b,j+S-i,n,:].(q_i+pb), then softmax,
// then out[h] = sum_j p[j] * v[b,j,n,h].  (rel_shift folded into the r index;
// l = j+S-i is always in [1, 2047], no masking needed.)
// ---------------------------------------------------------------------------
__global__ __launch_bounds__(256) void attn_kernel(
    const float* __restrict__ q, const float* __restrict__ k,
    const float* __restrict__ v, const float* __restrict__ r,
    const float* __restrict__ cb, const float* __restrict__ pb,
    float* __restrict__ attn)
{
    const int i   = blockIdx.x;
    const int n   = blockIdx.y;
    const int b   = blockIdx.z;
    const int tid = threadIdx.x;

    __shared__ float qc[64], qp[64];
    __shared__ float sc[1024];
    __shared__ float part[4][64];
    __shared__ float wred[4];

    if (tid < 64) {
        const float qv = q[((size_t)(b * Ss + i)) * NHh + n * 64 + tid];
        qc[tid] = qv + cb[n * 64 + tid];
        qp[tid] = qv + pb[n * 64 + tid];
    }
    __syncthreads();

    float myv[4];
    float lmax = -1e30f;
    #pragma unroll
    for (int jj = 0; jj < 4; ++jj) {
        const int j = tid + jj * 256;
        const float* kr = k + ((size_t)(b * Ss + j)) * NHh + n * 64;
        const float* rr = r + ((size_t)(b * Rr + (j + Ss - i))) * NHh + n * 64;
        float sacc = 0.f;
        #pragma unroll
        for (int h = 0; h < 64; h += 4) {
            const float4 kv = *reinterpret_cast<const float4*>(kr + h);
            const float4 rv = *reinterpret_cast<const float4*>(rr + h);
            sacc = fmaf(kv.x, qc[h + 0], sacc);
            sacc = fmaf(kv.y, qc[h + 1], sacc);
            sacc = fmaf(kv.z, qc[h + 2], sacc);
            sacc = fmaf(kv.w, qc[h + 3], sacc);
            sacc = fmaf(rv.x, qp[h + 0], sacc);
            sacc = fmaf(rv.y, qp[h + 1], sacc);
            sacc = fmaf(rv.z, qp[h + 2], sacc);
            sacc = fmaf(rv.w, qp[h + 3], sacc);
        }
        sacc *= 0.125f;   // 1/sqrt(H)
        myv[jj] = sacc;
        lmax = fmaxf(lmax, sacc);
    }

    // block max
    #pragma unroll
    for (int off = 32; off > 0; off >>= 1)
        lmax = fmaxf(lmax, __shfl_down(lmax, off));
    if ((tid & 63) == 0) wred[tid >> 6] = lmax;
    __syncthreads();
    const float gmax = fmaxf(fmaxf(wred[0], wred[1]), fmaxf(wred[2], wred[3]));
    __syncthreads();   // before reusing wred

    float lsum = 0.f;
    #pragma unroll
    for (int jj = 0; jj < 4; ++jj) {
        const int j = tid + jj * 256;
        const float e = __expf(myv[jj] - gmax);
        sc[j] = e;
        lsum += e;
    }
    #pragma unroll
    for (int off = 32; off > 0; off >>= 1)
        lsum += __shfl_down(lsum, off);
    if ((tid & 63) == 0) wred[tid >> 6] = lsum;
    __syncthreads();   // also publishes sc[]
    const float rsum = 1.f / (wred[0] + wred[1] + wred[2] + wred[3]);

    // P @ V: thread (h, g) accumulates quarter-range g for output channel h.
    const int h  = tid & 63;
    const int gq = tid >> 6;
    float pacc = 0.f;
    const float* vbase = v + ((size_t)(b * Ss)) * NHh + n * 64 + h;
    const int j0 = gq * 256;
    #pragma unroll 4
    for (int j = j0; j < j0 + 256; ++j)
        pacc = fmaf(sc[j], vbase[(size_t)j * NHh], pacc);
    part[gq][h] = pacc;
    __syncthreads();

    if (tid < 64) {
        const float o = (part[0][tid] + part[1][tid] + part[2][tid] + part[3][tid]) * rsum;
        attn[((size_t)(b * Ss + i)) * NHh + n * 64 + tid] = o;
    }
}

// ---------------------------------------------------------------------------
// Fused residual-add + LayerNorm over E=1024. One block per row, 256 threads.
// ---------------------------------------------------------------------------
__global__ __launch_bounds__(256) void add_ln_kernel(
    const float* __restrict__ a, const float* __restrict__ res,
    const float* __restrict__ g, const float* __restrict__ bet,
    float* __restrict__ out)
{
    const int row = blockIdx.x;
    const int tid = threadIdx.x;
    const float* ar = a   + (size_t)row * Ee;
    const float* rr = res + (size_t)row * Ee;

    float vals[4];
    float lsum = 0.f, lsq = 0.f;
    #pragma unroll
    for (int it = 0; it < 4; ++it) {
        const int idx = tid + it * 256;
        const float vv = ar[idx] + rr[idx];
        vals[it] = vv;
        lsum += vv;
        lsq  = fmaf(vv, vv, lsq);
    }
    #pragma unroll
    for (int off = 32; off > 0; off >>= 1) {
        lsum += __shfl_down(lsum, off);
        lsq  += __shfl_down(lsq,  off);
    }
    __shared__ float w1[4], w2[4];
    if ((tid & 63) == 0) { w1[tid >> 6] = lsum; w2[tid >> 6] = lsq; }
    __syncthreads();
    const float sum  = w1[0] + w1[1] + w1[2] + w1[3];
    const float sq   = w2[0] + w2[1] + w2[2] + w2[3];
    const float mean = sum * (1.f / 1024.f);
    const float var  = sq * (1.f / 1024.f) - mean * mean;
    const float rstd = rsqrtf(var + 1e-12f);
    #pragma unroll
    for (int it = 0; it < 4; ++it) {
        const int idx = tid + it * 256;
        out[(size_t)row * Ee + idx] = (vals[it] - mean) * rstd * g[idx] + bet[idx];
    }
}

// ---------------------------------------------------------------------------
// Orchestration.  Workspace layout (floats), 25,165,824 floats = 96 MiB:
//   [0        , 4194304 )  q            -> later reused: ao, then out2
//   [4194304  , 8388608 )  k            -> later reused: h (LN1 output)
//   [8388608  , 12582912)  v            \
//   [12582912 , 20971520)  r             } later reused: inner [4096,4096]
//   [20971520 , 25165824)  attn         /
// ---------------------------------------------------------------------------
extern "C" void kernel_launch(void* const* d_in, const int* in_sizes, int n_in,
                              void* d_out, int out_size, void* d_ws, size_t ws_size,
                              hipStream_t stream)
{
    (void)in_sizes; (void)n_in; (void)out_size; (void)ws_size;

    const float* x    = (const float*)d_in[0];
    const float* cb   = (const float*)d_in[1];
    const float* pb   = (const float*)d_in[2];
    const float* rpe  = (const float*)d_in[3];
    const float* Wq   = (const float*)d_in[4];
    const float* Wk   = (const float*)d_in[5];
    const float* Wv   = (const float*)d_in[6];
    const float* Wr   = (const float*)d_in[7];
    const float* Wo   = (const float*)d_in[8];
    const float* ln1g = (const float*)d_in[9];
    const float* ln1b = (const float*)d_in[10];
    const float* Wi   = (const float*)d_in[11];
    const float* bi   = (const float*)d_in[12];
    const float* Wout = (const float*)d_in[13];
    const float* bout = (const float*)d_in[14];
    const float* ln2g = (const float*)d_in[15];
    const float* ln2b = (const float*)d_in[16];

    float* out = (float*)d_out;
    float* ws  = (float*)d_ws;

    float* qb     = ws;               // 4,194,304
    float* kb     = ws + 4194304;
    float* vb     = ws + 8388608;
    float* rb     = ws + 12582912;    // 8,388,608
    float* attnb  = ws + 20971520;    // 4,194,304
    float* aob    = ws;               // reuse q
    float* hb     = ws + 4194304;     // reuse k
    float* innerb = ws + 8388608;     // 16,777,216 (reuse v+r+attn)
    float* out2   = ws;               // reuse ao

    const dim3 blk(256);

    // Projections: [BS,E] @ [E,NH]
    gemm_f32<0,0><<<dim3(NHh/64, BSs/128), blk, 0, stream>>>(x,   Wq, nullptr, qb, BSs, NHh, Ee);
    gemm_f32<0,0><<<dim3(NHh/64, BSs/128), blk, 0, stream>>>(x,   Wk, nullptr, kb, BSs, NHh, Ee);
    gemm_f32<0,0><<<dim3(NHh/64, BSs/128), blk, 0, stream>>>(x,   Wv, nullptr, vb, BSs, NHh, Ee);
    gemm_f32<0,0><<<dim3(NHh/64, (Bb*Rr)/128), blk, 0, stream>>>(rpe, Wr, nullptr, rb, Bb*Rr, NHh, Ee);

    // Attention core (scores + rel-shift + softmax + PV)
    attn_kernel<<<dim3(Ss, Nn, Bb), blk, 0, stream>>>(qb, kb, vb, rb, cb, pb, attnb);

    // Output projection: [BS,NH] @ [NH,E]   (Wo is [N,H,E] == row-major [NH,E])
    gemm_f32<0,0><<<dim3(Ee/64, BSs/128), blk, 0, stream>>>(attnb, Wo, nullptr, aob, BSs, Ee, NHh);

    // h = LN1(ao + x)
    add_ln_kernel<<<dim3(BSs), blk, 0, stream>>>(aob, x, ln1g, ln1b, hb);

    // FFN
    gemm_f32<1,1><<<dim3(Ff/64, BSs/128), blk, 0, stream>>>(hb, Wi, bi, innerb, BSs, Ff, Ee);
    gemm_f32<1,0><<<dim3(Ee/64, BSs/128), blk, 0, stream>>>(innerb, Wout, bout, out2, BSs, Ee, Ff);

    // out = LN2(out2 + h)
    add_ln_kernel<<<dim3(BSs), blk, 0, stream>>>(out2, hb, ln2g, ln2b, out);
}

// Round 2
// 2320.540 us; speedup vs baseline: 4.5398x; 4.5398x over previous
//
#include <hip/hip_runtime.h>
#include <math.h>

// Problem constants
#define Bb   4
#define Ss   1024
#define Ee   1024
#define Nn   16
#define Hh   64
#define Ff   4096
#define Rr   2048
#define NHh  1024   // N*H
#define BSs  4096   // B*S

// ---------------------------------------------------------------------------
// Generic fp32 GEMM: C[M,N] = A[M,K] @ B[K,N] (+ bias) (+ relu)
// Tile: 128(M) x 64(N) x 16(K), 256 threads, 8x4 micro-tile per thread.
// ---------------------------------------------------------------------------
template<int BIAS, int RELU>
__global__ __launch_bounds__(256) void gemm_f32(
    const float* __restrict__ A, const float* __restrict__ Bm,
    const float* __restrict__ bias, float* __restrict__ C,
    int M, int N, int K)
{
    __shared__ float As[16][128];   // [k][m]
    __shared__ float Bs[16][64];    // [k][n]

    const int tid  = threadIdx.x;
    const int row0 = blockIdx.y * 128;
    const int col0 = blockIdx.x * 64;
    const int tm   = tid >> 4;
    const int tn   = tid & 15;

    float acc[8][4] = {{0.f}};

    for (int k0 = 0; k0 < K; k0 += 16) {
        {
            const int m  = tid >> 1;
            const int kk = (tid & 1) * 8;
            const float* ap = A + (size_t)(row0 + m) * K + (k0 + kk);
            const float4 a0 = *reinterpret_cast<const float4*>(ap);
            const float4 a1 = *reinterpret_cast<const float4*>(ap + 4);
            As[kk+0][m] = a0.x; As[kk+1][m] = a0.y;
            As[kk+2][m] = a0.z; As[kk+3][m] = a0.w;
            As[kk+4][m] = a1.x; As[kk+5][m] = a1.y;
            As[kk+6][m] = a1.z; As[kk+7][m] = a1.w;
        }
        {
            const int kk = tid >> 4;
            const int nn = (tid & 15) * 4;
            *reinterpret_cast<float4*>(&Bs[kk][nn]) =
                *reinterpret_cast<const float4*>(Bm + (size_t)(k0 + kk) * N + col0 + nn);
        }
        __syncthreads();

        #pragma unroll
        for (int kk = 0; kk < 16; ++kk) {
            float a[8], bv[4];
            *reinterpret_cast<float4*>(&a[0]) =
                *reinterpret_cast<const float4*>(&As[kk][tm * 8]);
            *reinterpret_cast<float4*>(&a[4]) =
                *reinterpret_cast<const float4*>(&As[kk][tm * 8 + 4]);
            *reinterpret_cast<float4*>(&bv[0]) =
                *reinterpret_cast<const float4*>(&Bs[kk][tn * 4]);
            #pragma unroll
            for (int i = 0; i < 8; ++i)
                #pragma unroll
                for (int j = 0; j < 4; ++j)
                    acc[i][j] = fmaf(a[i], bv[j], acc[i][j]);
        }
        __syncthreads();
    }

    float bv[4] = {0.f, 0.f, 0.f, 0.f};
    if (BIAS) {
        const float4 bb = *reinterpret_cast<const float4*>(&bias[col0 + tn * 4]);
        bv[0] = bb.x; bv[1] = bb.y; bv[2] = bb.z; bv[3] = bb.w;
    }
    #pragma unroll
    for (int i = 0; i < 8; ++i) {
        const int row = row0 + tm * 8 + i;
        float4 o;
        float t0 = acc[i][0] + bv[0];
        float t1 = acc[i][1] + bv[1];
        float t2 = acc[i][2] + bv[2];
        float t3 = acc[i][3] + bv[3];
        if (RELU) {
            t0 = fmaxf(t0, 0.f); t1 = fmaxf(t1, 0.f);
            t2 = fmaxf(t2, 0.f); t3 = fmaxf(t3, 0.f);
        }
        o.x = t0; o.y = t1; o.z = t2; o.w = t3;
        *reinterpret_cast<float4*>(C + (size_t)row * N + col0 + tn * 4) = o;
    }
}

// ---------------------------------------------------------------------------
// Flash-style attention, fp32 from LDS.
// Block = (i-tile of 32 queries, n, b); 256 threads.
// Loops over 32-key tiles; stages K, V, and the rel-shift R-band in LDS.
// scores(ii,jj) = qc[ii].K[jj] + qp[ii].Rb[jj-ii+31], online softmax, O += P@V.
//   (rel_shift folded: shifted[i][j] = pos[i][j+S-i], l = j+S-i in [1,2047])
// Thread map: ii = tid>>3 (query row), g = tid&7; scores jj = g+8u (u=0..3);
// O columns h = g*8+u (u=0..7). Pad LDS rows to 68 floats (bank stride 4).
// ---------------------------------------------------------------------------
#define TM 32
#define TJ 32
#define PADW 68

__global__ __launch_bounds__(256) void attn_kernel(
    const float* __restrict__ q, const float* __restrict__ k,
    const float* __restrict__ v, const float* __restrict__ r,
    const float* __restrict__ cb, const float* __restrict__ pb,
    float* __restrict__ attn)
{
    const int i0  = blockIdx.x * TM;
    const int n   = blockIdx.y;
    const int b   = blockIdx.z;
    const int tid = threadIdx.x;
    const int ii  = tid >> 3;   // 0..31 query row
    const int g   = tid & 7;    // 0..7

    __shared__ float qc[TM][PADW], qp[TM][PADW];
    __shared__ float Kt[TJ][PADW], Vt[TJ][PADW];
    __shared__ float Rbs[64][PADW];
    __shared__ float Pt[TM][PADW];

    // Stage q tile (+biases): row = tid>>3, 8 lanes x 8 floats
    {
        const int row = tid >> 3;
        const int c0  = (tid & 7) * 8;
        const float* qr  = q + ((size_t)(b * Ss + i0 + row)) * NHh + n * 64 + c0;
        const float* cbp = cb + n * 64 + c0;
        const float* pbp = pb + n * 64 + c0;
        #pragma unroll
        for (int u = 0; u < 8; ++u) {
            const float qv = qr[u];
            qc[row][c0 + u] = qv + cbp[u];
            qp[row][c0 + u] = qv + pbp[u];
        }
    }

    float m_i = -1e30f, l_i = 0.f;
    float O[8] = {0.f, 0.f, 0.f, 0.f, 0.f, 0.f, 0.f, 0.f};

    for (int j0 = 0; j0 < Ss; j0 += TJ) {
        __syncthreads();   // previous PV done before restaging
        // Stage K, V tiles: row = tid>>3, cols (tid&7)*8 .. +7
        {
            const int row = tid >> 3;
            const int c0  = (tid & 7) * 8;
            const size_t goff = ((size_t)(b * Ss + j0 + row)) * NHh + n * 64 + c0;
            const float4 k0v = *reinterpret_cast<const float4*>(k + goff);
            const float4 k1v = *reinterpret_cast<const float4*>(k + goff + 4);
            const float4 v0v = *reinterpret_cast<const float4*>(v + goff);
            const float4 v1v = *reinterpret_cast<const float4*>(v + goff + 4);
            *reinterpret_cast<float4*>(&Kt[row][c0])     = k0v;
            *reinterpret_cast<float4*>(&Kt[row][c0 + 4]) = k1v;
            *reinterpret_cast<float4*>(&Vt[row][c0])     = v0v;
            *reinterpret_cast<float4*>(&Vt[row][c0 + 4]) = v1v;
        }
        // Stage R band: rows 0..62 hold l = l_min + row
        {
            const int row = tid >> 2;          // 0..63
            const int c0  = (tid & 3) * 16;
            if (row < 63) {
                const int l = j0 + Ss - i0 - (TM - 1) + row;   // in [1,2047]
                const float* rp = r + ((size_t)(b * Rr + l)) * NHh + n * 64 + c0;
                #pragma unroll
                for (int u = 0; u < 4; ++u)
                    *reinterpret_cast<float4*>(&Rbs[row][c0 + u * 4]) =
                        *reinterpret_cast<const float4*>(rp + u * 4);
            }
        }
        __syncthreads();

        // Scores: 4 per thread, jj = g + 8u
        float s[4] = {0.f, 0.f, 0.f, 0.f};
        #pragma unroll
        for (int h = 0; h < 64; h += 4) {
            const float4 qc4 = *reinterpret_cast<const float4*>(&qc[ii][h]);
            const float4 qp4 = *reinterpret_cast<const float4*>(&qp[ii][h]);
            #pragma unroll
            for (int u = 0; u < 4; ++u) {
                const int jj = g + 8 * u;
                const float4 kt4 = *reinterpret_cast<const float4*>(&Kt[jj][h]);
                const float4 rb4 = *reinterpret_cast<const float4*>(&Rbs[jj - ii + 31][h]);
                float acc = s[u];
                acc = fmaf(qc4.x, kt4.x, acc);
                acc = fmaf(qc4.y, kt4.y, acc);
                acc = fmaf(qc4.z, kt4.z, acc);
                acc = fmaf(qc4.w, kt4.w, acc);
                acc = fmaf(qp4.x, rb4.x, acc);
                acc = fmaf(qp4.y, rb4.y, acc);
                acc = fmaf(qp4.z, rb4.z, acc);
                acc = fmaf(qp4.w, rb4.w, acc);
                s[u] = acc;
            }
        }
        #pragma unroll
        for (int u = 0; u < 4; ++u) s[u] *= 0.125f;

        // Row max across the 8-lane group
        float tmax = fmaxf(fmaxf(s[0], s[1]), fmaxf(s[2], s[3]));
        tmax = fmaxf(tmax, __shfl_down(tmax, 4, 8));
        tmax = fmaxf(tmax, __shfl_down(tmax, 2, 8));
        tmax = fmaxf(tmax, __shfl_down(tmax, 1, 8));
        tmax = __shfl(tmax, 0, 8);

        const float m_new = fmaxf(m_i, tmax);
        const float alpha = __expf(m_i - m_new);
        float p[4], psum = 0.f;
        #pragma unroll
        for (int u = 0; u < 4; ++u) {
            p[u] = __expf(s[u] - m_new);
            psum += p[u];
        }
        psum += __shfl_down(psum, 4, 8);
        psum += __shfl_down(psum, 2, 8);
        psum += __shfl_down(psum, 1, 8);
        psum = __shfl(psum, 0, 8);
        l_i = l_i * alpha + psum;
        m_i = m_new;

        #pragma unroll
        for (int u = 0; u < 4; ++u) Pt[ii][g + 8 * u] = p[u];
        #pragma unroll
        for (int u = 0; u < 8; ++u) O[u] *= alpha;
        __syncthreads();   // publish Pt

        // PV: thread (ii,g) accumulates O[ii][g*8+u]
        #pragma unroll 8
        for (int jj2 = 0; jj2 < TJ; ++jj2) {
            const float pv = Pt[ii][jj2];
            const float4 v4a = *reinterpret_cast<const float4*>(&Vt[jj2][g * 8]);
            const float4 v4b = *reinterpret_cast<const float4*>(&Vt[jj2][g * 8 + 4]);
            O[0] = fmaf(pv, v4a.x, O[0]);
            O[1] = fmaf(pv, v4a.y, O[1]);
            O[2] = fmaf(pv, v4a.z, O[2]);
            O[3] = fmaf(pv, v4a.w, O[3]);
            O[4] = fmaf(pv, v4b.x, O[4]);
            O[5] = fmaf(pv, v4b.y, O[5]);
            O[6] = fmaf(pv, v4b.z, O[6]);
            O[7] = fmaf(pv, v4b.w, O[7]);
        }
    }

    // Finalize
    const float inv = 1.f / l_i;
    float4 o0, o1;
    o0.x = O[0] * inv; o0.y = O[1] * inv; o0.z = O[2] * inv; o0.w = O[3] * inv;
    o1.x = O[4] * inv; o1.y = O[5] * inv; o1.z = O[6] * inv; o1.w = O[7] * inv;
    float* op = attn + ((size_t)(b * Ss + i0 + ii)) * NHh + n * 64 + g * 8;
    *reinterpret_cast<float4*>(op)     = o0;
    *reinterpret_cast<float4*>(op + 4) = o1;
}

// ---------------------------------------------------------------------------
// Fused residual-add + LayerNorm over E=1024. One block per row, 256 threads.
// ---------------------------------------------------------------------------
__global__ __launch_bounds__(256) void add_ln_kernel(
    const float* __restrict__ a, const float* __restrict__ res,
    const float* __restrict__ g, const float* __restrict__ bet,
    float* __restrict__ out)
{
    const int row = blockIdx.x;
    const int tid = threadIdx.x;
    const float* ar = a   + (size_t)row * Ee;
    const float* rr = res + (size_t)row * Ee;

    float vals[4];
    float lsum = 0.f, lsq = 0.f;
    #pragma unroll
    for (int it = 0; it < 4; ++it) {
        const int idx = tid + it * 256;
        const float vv = ar[idx] + rr[idx];
        vals[it] = vv;
        lsum += vv;
        lsq  = fmaf(vv, vv, lsq);
    }
    #pragma unroll
    for (int off = 32; off > 0; off >>= 1) {
        lsum += __shfl_down(lsum, off);
        lsq  += __shfl_down(lsq,  off);
    }
    __shared__ float w1[4], w2[4];
    if ((tid & 63) == 0) { w1[tid >> 6] = lsum; w2[tid >> 6] = lsq; }
    __syncthreads();
    const float sum  = w1[0] + w1[1] + w1[2] + w1[3];
    const float sq   = w2[0] + w2[1] + w2[2] + w2[3];
    const float mean = sum * (1.f / 1024.f);
    const float var  = sq * (1.f / 1024.f) - mean * mean;
    const float rstd = rsqrtf(var + 1e-12f);
    #pragma unroll
    for (int it = 0; it < 4; ++it) {
        const int idx = tid + it * 256;
        out[(size_t)row * Ee + idx] = (vals[it] - mean) * rstd * g[idx] + bet[idx];
    }
}

// ---------------------------------------------------------------------------
// Orchestration.  Workspace layout (floats), 25,165,824 floats = 96 MiB:
//   [0        , 4194304 )  q            -> later reused: ao, then out2
//   [4194304  , 8388608 )  k            -> later reused: h (LN1 output)
//   [8388608  , 12582912)  v            \
//   [12582912 , 20971520)  r             } later reused: inner [4096,4096]
//   [20971520 , 25165824)  attn         /
// ---------------------------------------------------------------------------
extern "C" void kernel_launch(void* const* d_in, const int* in_sizes, int n_in,
                              void* d_out, int out_size, void* d_ws, size_t ws_size,
                              hipStream_t stream)
{
    (void)in_sizes; (void)n_in; (void)out_size; (void)ws_size;

    const float* x    = (const float*)d_in[0];
    const float* cb   = (const float*)d_in[1];
    const float* pb   = (const float*)d_in[2];
    const float* rpe  = (const float*)d_in[3];
    const float* Wq   = (const float*)d_in[4];
    const float* Wk   = (const float*)d_in[5];
    const float* Wv   = (const float*)d_in[6];
    const float* Wr   = (const float*)d_in[7];
    const float* Wo   = (const float*)d_in[8];
    const float* ln1g = (const float*)d_in[9];
    const float* ln1b = (const float*)d_in[10];
    const float* Wi   = (const float*)d_in[11];
    const float* bi   = (const float*)d_in[12];
    const float* Wout = (const float*)d_in[13];
    const float* bout = (const float*)d_in[14];
    const float* ln2g = (const float*)d_in[15];
    const float* ln2b = (const float*)d_in[16];

    float* out = (float*)d_out;
    float* ws  = (float*)d_ws;

    float* qb     = ws;               // 4,194,304
    float* kb     = ws + 4194304;
    float* vb     = ws + 8388608;
    float* rb     = ws + 12582912;    // 8,388,608
    float* attnb  = ws + 20971520;    // 4,194,304
    float* aob    = ws;               // reuse q
    float* hb     = ws + 4194304;     // reuse k
    float* innerb = ws + 8388608;     // 16,777,216 (reuse v+r+attn)
    float* out2   = ws;               // reuse ao

    const dim3 blk(256);

    // Projections: [BS,E] @ [E,NH]
    gemm_f32<0,0><<<dim3(NHh/64, BSs/128), blk, 0, stream>>>(x,   Wq, nullptr, qb, BSs, NHh, Ee);
    gemm_f32<0,0><<<dim3(NHh/64, BSs/128), blk, 0, stream>>>(x,   Wk, nullptr, kb, BSs, NHh, Ee);
    gemm_f32<0,0><<<dim3(NHh/64, BSs/128), blk, 0, stream>>>(x,   Wv, nullptr, vb, BSs, NHh, Ee);
    gemm_f32<0,0><<<dim3(NHh/64, (Bb*Rr)/128), blk, 0, stream>>>(rpe, Wr, nullptr, rb, Bb*Rr, NHh, Ee);

    // Attention core (scores + rel-shift + online softmax + PV)
    attn_kernel<<<dim3(Ss/TM, Nn, Bb), blk, 0, stream>>>(qb, kb, vb, rb, cb, pb, attnb);

    // Output projection: [BS,NH] @ [NH,E]   (Wo is [N,H,E] == row-major [NH,E])
    gemm_f32<0,0><<<dim3(Ee/64, BSs/128), blk, 0, stream>>>(attnb, Wo, nullptr, aob, BSs, Ee, NHh);

    // h = LN1(ao + x)
    add_ln_kernel<<<dim3(BSs), blk, 0, stream>>>(aob, x, ln1g, ln1b, hb);

    // FFN
    gemm_f32<1,1><<<dim3(Ff/64, BSs/128), blk, 0, stream>>>(hb, Wi, bi, innerb, BSs, Ff, Ee);
    gemm_f32<1,0><<<dim3(Ee/64, BSs/128), blk, 0, stream>>>(innerb, Wout, bout, out2, BSs, Ee, Ff);

    // out = LN2(out2 + h)
    add_ln_kernel<<<dim3(BSs), blk, 0, stream>>>(out2, hb, ln2g, ln2b, out);
}

// Round 3
// 1152.532 us; speedup vs baseline: 9.1405x; 2.0134x over previous
//
#include <hip/hip_runtime.h>
#include <math.h>

// Problem constants
#define Bb   4
#define Ss   1024
#define Ee   1024
#define Nn   16
#define Hh   64
#define Ff   4096
#define Rr   2048
#define NHh  1024   // N*H
#define BSs  4096   // B*S

typedef short v8s __attribute__((ext_vector_type(8)));
typedef float v4f __attribute__((ext_vector_type(4)));
typedef unsigned int u32;

static __device__ inline unsigned short f2bf(float f) {
    u32 u = __builtin_bit_cast(u32, f);
    u += 0x7fffu + ((u >> 16) & 1u);   // RNE
    return (unsigned short)(u >> 16);
}
static __device__ inline float bf2f(unsigned short h) {
    u32 u = ((u32)h) << 16;
    return __builtin_bit_cast(float, u);
}
static __device__ inline void g2lds16(const void* g, void* l) {
    __builtin_amdgcn_global_load_lds(
        (const __attribute__((address_space(1))) u32*)g,
        (__attribute__((address_space(3))) u32*)l, 16, 0, 0);
}

// ---------------------------------------------------------------------------
// fp32 -> bf16 elementwise (4 elems/thread)
// ---------------------------------------------------------------------------
__global__ __launch_bounds__(256) void cvt_f32_bf16(
    const float* __restrict__ in, unsigned short* __restrict__ out)
{
    const size_t i = ((size_t)blockIdx.x * 256 + threadIdx.x) * 4;
    const float4 v = *reinterpret_cast<const float4*>(in + i);
    ushort4 o;
    o.x = f2bf(v.x); o.y = f2bf(v.y); o.z = f2bf(v.z); o.w = f2bf(v.w);
    *reinterpret_cast<ushort4*>(out + i) = o;
}

// ---------------------------------------------------------------------------
// Transpose + cvt: in [K][N] fp32 -> out [N][K] bf16. Grid (N/32, K/32).
// ---------------------------------------------------------------------------
__global__ __launch_bounds__(256) void tr_cvt(
    const float* __restrict__ in, unsigned short* __restrict__ out, int K, int N)
{
    __shared__ float t[32][33];
    const int j0 = blockIdx.x * 32, i0 = blockIdx.y * 32;
    const int r  = threadIdx.x >> 3;
    const int c4 = (threadIdx.x & 7) * 4;
    const float4 v = *reinterpret_cast<const float4*>(in + (size_t)(i0 + r) * N + j0 + c4);
    t[r][c4 + 0] = v.x; t[r][c4 + 1] = v.y; t[r][c4 + 2] = v.z; t[r][c4 + 3] = v.w;
    __syncthreads();
    ushort4 o;
    o.x = f2bf(t[c4 + 0][r]); o.y = f2bf(t[c4 + 1][r]);
    o.z = f2bf(t[c4 + 2][r]); o.w = f2bf(t[c4 + 3][r]);
    *reinterpret_cast<ushort4*>(out + (size_t)(j0 + r) * K + i0 + c4) = o;
}

// ---------------------------------------------------------------------------
// bf16 MFMA GEMM (m97 structure): C[M,N] = A[M,K] @ B^T  (B given as [N][K]).
// 128x128 tile, BK=32, 256 thr / 4 waves (2x2), each wave 4x4 of 16x16x32.
// global_load_lds width=16 staging; ds_read_b128 fragments; fp32 acc.
// C/D layout: col = lane&15, row = (lane>>4)*4 + reg.
// ---------------------------------------------------------------------------
template<int OUT_BF16, int BIAS, int RELU>
__global__ __launch_bounds__(256) void gemm_mfma(
    const unsigned short* __restrict__ A, const unsigned short* __restrict__ B,
    const float* __restrict__ bias, void* __restrict__ Cv,
    int M, int N, int K)
{
    __shared__ unsigned short Asm[128 * 32];
    __shared__ unsigned short Bsm[128 * 32];

    const int tid  = threadIdx.x;
    const int lane = tid & 63;
    const int wave = tid >> 6;
    const int wr   = wave >> 1, wc = wave & 1;
    const int row0 = blockIdx.y * 128, col0 = blockIdx.x * 128;
    const int lrow = lane & 15;
    const int lq   = lane >> 4;

    v4f acc[4][4];
    #pragma unroll
    for (int mt = 0; mt < 4; ++mt)
        #pragma unroll
        for (int nt = 0; nt < 4; ++nt)
            acc[mt][nt] = (v4f){0.f, 0.f, 0.f, 0.f};

    // staging chunks: chunk c (0..511) -> row c>>2, k-offset (c&3)*8
    const int ca = tid, cb2 = tid + 256;
    const int ra = ca >> 2,  ka = (ca & 3) * 8;
    const int rb = cb2 >> 2, kb = (cb2 & 3) * 8;

    for (int k0 = 0; k0 < K; k0 += 32) {
        g2lds16(A + (size_t)(row0 + ra) * K + k0 + ka, &Asm[ca * 8]);
        g2lds16(A + (size_t)(row0 + rb) * K + k0 + kb, &Asm[cb2 * 8]);
        g2lds16(B + (size_t)(col0 + ra) * K + k0 + ka, &Bsm[ca * 8]);
        g2lds16(B + (size_t)(col0 + rb) * K + k0 + kb, &Bsm[cb2 * 8]);
        __syncthreads();

        v8s af[4], bf[4];
        #pragma unroll
        for (int mt = 0; mt < 4; ++mt)
            af[mt] = *reinterpret_cast<const v8s*>(&Asm[(wr * 64 + mt * 16 + lrow) * 32 + lq * 8]);
        #pragma unroll
        for (int nt = 0; nt < 4; ++nt)
            bf[nt] = *reinterpret_cast<const v8s*>(&Bsm[(wc * 64 + nt * 16 + lrow) * 32 + lq * 8]);
        #pragma unroll
        for (int mt = 0; mt < 4; ++mt)
            #pragma unroll
            for (int nt = 0; nt < 4; ++nt)
                acc[mt][nt] = __builtin_amdgcn_mfma_f32_16x16x32_bf16(
                    af[mt], bf[nt], acc[mt][nt], 0, 0, 0);
        __syncthreads();
    }

    #pragma unroll
    for (int nt = 0; nt < 4; ++nt) {
        const int col = col0 + wc * 64 + nt * 16 + lrow;
        const float bv = BIAS ? bias[col] : 0.f;
        #pragma unroll
        for (int mt = 0; mt < 4; ++mt) {
            #pragma unroll
            for (int v = 0; v < 4; ++v) {
                const int row = row0 + wr * 64 + mt * 16 + lq * 4 + v;
                float val = acc[mt][nt][v] + bv;
                if (RELU) val = fmaxf(val, 0.f);
                if (OUT_BF16)
                    ((unsigned short*)Cv)[(size_t)row * N + col] = f2bf(val);
                else
                    ((float*)Cv)[(size_t)row * N + col] = val;
            }
        }
    }
}

// ---------------------------------------------------------------------------
// Flash-style attention; q/k/v/r are bf16 in HBM, fp32 in LDS and math.
// Block = (32-query tile, n, b); 256 threads; 32-key tiles.
// rel_shift folded: shifted[i][j] = pos[i][j+S-i], l in [1,2047].
// ---------------------------------------------------------------------------
#define TM 32
#define TJ 32
#define PADW 68

__global__ __launch_bounds__(256) void attn_kernel(
    const unsigned short* __restrict__ q, const unsigned short* __restrict__ k,
    const unsigned short* __restrict__ v, const unsigned short* __restrict__ r,
    const float* __restrict__ cb, const float* __restrict__ pb,
    unsigned short* __restrict__ attn)
{
    const int i0  = blockIdx.x * TM;
    const int n   = blockIdx.y;
    const int b   = blockIdx.z;
    const int tid = threadIdx.x;
    const int ii  = tid >> 3;
    const int g   = tid & 7;

    __shared__ float qc[TM][PADW], qp[TM][PADW];
    __shared__ float Kt[TJ][PADW], Vt[TJ][PADW];
    __shared__ float Rbs[64][PADW];
    __shared__ float Pt[TM][PADW];

    {
        const int row = tid >> 3;
        const int c0  = (tid & 7) * 8;
        const unsigned short* qr = q + ((size_t)(b * Ss + i0 + row)) * NHh + n * 64 + c0;
        const float* cbp = cb + n * 64 + c0;
        const float* pbp = pb + n * 64 + c0;
        const ushort4 qa = *reinterpret_cast<const ushort4*>(qr);
        const ushort4 qb = *reinterpret_cast<const ushort4*>(qr + 4);
        float qf[8] = {bf2f(qa.x), bf2f(qa.y), bf2f(qa.z), bf2f(qa.w),
                       bf2f(qb.x), bf2f(qb.y), bf2f(qb.z), bf2f(qb.w)};
        #pragma unroll
        for (int u = 0; u < 8; ++u) {
            qc[row][c0 + u] = qf[u] + cbp[u];
            qp[row][c0 + u] = qf[u] + pbp[u];
        }
    }

    float m_i = -1e30f, l_i = 0.f;
    float O[8] = {0.f, 0.f, 0.f, 0.f, 0.f, 0.f, 0.f, 0.f};

    for (int j0 = 0; j0 < Ss; j0 += TJ) {
        __syncthreads();
        {
            const int row = tid >> 3;
            const int c0  = (tid & 7) * 8;
            const size_t goff = ((size_t)(b * Ss + j0 + row)) * NHh + n * 64 + c0;
            const ushort4 ka4 = *reinterpret_cast<const ushort4*>(k + goff);
            const ushort4 kb4 = *reinterpret_cast<const ushort4*>(k + goff + 4);
            const ushort4 va4 = *reinterpret_cast<const ushort4*>(v + goff);
            const ushort4 vb4 = *reinterpret_cast<const ushort4*>(v + goff + 4);
            Kt[row][c0+0] = bf2f(ka4.x); Kt[row][c0+1] = bf2f(ka4.y);
            Kt[row][c0+2] = bf2f(ka4.z); Kt[row][c0+3] = bf2f(ka4.w);
            Kt[row][c0+4] = bf2f(kb4.x); Kt[row][c0+5] = bf2f(kb4.y);
            Kt[row][c0+6] = bf2f(kb4.z); Kt[row][c0+7] = bf2f(kb4.w);
            Vt[row][c0+0] = bf2f(va4.x); Vt[row][c0+1] = bf2f(va4.y);
            Vt[row][c0+2] = bf2f(va4.z); Vt[row][c0+3] = bf2f(va4.w);
            Vt[row][c0+4] = bf2f(vb4.x); Vt[row][c0+5] = bf2f(vb4.y);
            Vt[row][c0+6] = bf2f(vb4.z); Vt[row][c0+7] = bf2f(vb4.w);
        }
        {
            const int row = tid >> 2;
            const int c0  = (tid & 3) * 16;
            if (row < 63) {
                const int l = j0 + Ss - i0 - (TM - 1) + row;
                const unsigned short* rp = r + ((size_t)(b * Rr + l)) * NHh + n * 64 + c0;
                #pragma unroll
                for (int u = 0; u < 4; ++u) {
                    const ushort4 rv = *reinterpret_cast<const ushort4*>(rp + u * 4);
                    Rbs[row][c0 + u*4 + 0] = bf2f(rv.x);
                    Rbs[row][c0 + u*4 + 1] = bf2f(rv.y);
                    Rbs[row][c0 + u*4 + 2] = bf2f(rv.z);
                    Rbs[row][c0 + u*4 + 3] = bf2f(rv.w);
                }
            }
        }
        __syncthreads();

        float s[4] = {0.f, 0.f, 0.f, 0.f};
        #pragma unroll
        for (int h = 0; h < 64; h += 4) {
            const float4 qc4 = *reinterpret_cast<const float4*>(&qc[ii][h]);
            const float4 qp4 = *reinterpret_cast<const float4*>(&qp[ii][h]);
            #pragma unroll
            for (int u = 0; u < 4; ++u) {
                const int jj = g + 8 * u;
                const float4 kt4 = *reinterpret_cast<const float4*>(&Kt[jj][h]);
                const float4 rb4 = *reinterpret_cast<const float4*>(&Rbs[jj - ii + 31][h]);
                float acc = s[u];
                acc = fmaf(qc4.x, kt4.x, acc);
                acc = fmaf(qc4.y, kt4.y, acc);
                acc = fmaf(qc4.z, kt4.z, acc);
                acc = fmaf(qc4.w, kt4.w, acc);
                acc = fmaf(qp4.x, rb4.x, acc);
                acc = fmaf(qp4.y, rb4.y, acc);
                acc = fmaf(qp4.z, rb4.z, acc);
                acc = fmaf(qp4.w, rb4.w, acc);
                s[u] = acc;
            }
        }
        #pragma unroll
        for (int u = 0; u < 4; ++u) s[u] *= 0.125f;

        float tmax = fmaxf(fmaxf(s[0], s[1]), fmaxf(s[2], s[3]));
        tmax = fmaxf(tmax, __shfl_down(tmax, 4, 8));
        tmax = fmaxf(tmax, __shfl_down(tmax, 2, 8));
        tmax = fmaxf(tmax, __shfl_down(tmax, 1, 8));
        tmax = __shfl(tmax, 0, 8);

        const float m_new = fmaxf(m_i, tmax);
        const float alpha = __expf(m_i - m_new);
        float p[4], psum = 0.f;
        #pragma unroll
        for (int u = 0; u < 4; ++u) {
            p[u] = __expf(s[u] - m_new);
            psum += p[u];
        }
        psum += __shfl_down(psum, 4, 8);
        psum += __shfl_down(psum, 2, 8);
        psum += __shfl_down(psum, 1, 8);
        psum = __shfl(psum, 0, 8);
        l_i = l_i * alpha + psum;
        m_i = m_new;

        #pragma unroll
        for (int u = 0; u < 4; ++u) Pt[ii][g + 8 * u] = p[u];
        #pragma unroll
        for (int u = 0; u < 8; ++u) O[u] *= alpha;
        __syncthreads();

        #pragma unroll 8
        for (int jj2 = 0; jj2 < TJ; ++jj2) {
            const float pv = Pt[ii][jj2];
            const float4 v4a = *reinterpret_cast<const float4*>(&Vt[jj2][g * 8]);
            const float4 v4b = *reinterpret_cast<const float4*>(&Vt[jj2][g * 8 + 4]);
            O[0] = fmaf(pv, v4a.x, O[0]);
            O[1] = fmaf(pv, v4a.y, O[1]);
            O[2] = fmaf(pv, v4a.z, O[2]);
            O[3] = fmaf(pv, v4a.w, O[3]);
            O[4] = fmaf(pv, v4b.x, O[4]);
            O[5] = fmaf(pv, v4b.y, O[5]);
            O[6] = fmaf(pv, v4b.z, O[6]);
            O[7] = fmaf(pv, v4b.w, O[7]);
        }
    }

    const float inv = 1.f / l_i;
    ushort4 o0, o1;
    o0.x = f2bf(O[0] * inv); o0.y = f2bf(O[1] * inv);
    o0.z = f2bf(O[2] * inv); o0.w = f2bf(O[3] * inv);
    o1.x = f2bf(O[4] * inv); o1.y = f2bf(O[5] * inv);
    o1.z = f2bf(O[6] * inv); o1.w = f2bf(O[7] * inv);
    unsigned short* op = attn + ((size_t)(b * Ss + i0 + ii)) * NHh + n * 64 + g * 8;
    *reinterpret_cast<ushort4*>(op)     = o0;
    *reinterpret_cast<ushort4*>(op + 4) = o1;
}

// ---------------------------------------------------------------------------
// Fused residual-add + LayerNorm over E=1024; optional bf16 copy of output.
// ---------------------------------------------------------------------------
template<int W16>
__global__ __launch_bounds__(256) void add_ln_kernel(
    const float* __restrict__ a, const float* __restrict__ res,
    const float* __restrict__ g, const float* __restrict__ bet,
    float* __restrict__ out, unsigned short* __restrict__ out16)
{
    const int row = blockIdx.x;
    const int tid = threadIdx.x;
    const float* ar = a   + (size_t)row * Ee;
    const float* rr = res + (size_t)row * Ee;

    float vals[4];
    float lsum = 0.f, lsq = 0.f;
    #pragma unroll
    for (int it = 0; it < 4; ++it) {
        const int idx = tid + it * 256;
        const float vv = ar[idx] + rr[idx];
        vals[it] = vv;
        lsum += vv;
        lsq  = fmaf(vv, vv, lsq);
    }
    #pragma unroll
    for (int off = 32; off > 0; off >>= 1) {
        lsum += __shfl_down(lsum, off);
        lsq  += __shfl_down(lsq,  off);
    }
    __shared__ float w1[4], w2[4];
    if ((tid & 63) == 0) { w1[tid >> 6] = lsum; w2[tid >> 6] = lsq; }
    __syncthreads();
    const float sum  = w1[0] + w1[1] + w1[2] + w1[3];
    const float sq   = w2[0] + w2[1] + w2[2] + w2[3];
    const float mean = sum * (1.f / 1024.f);
    const float var  = sq * (1.f / 1024.f) - mean * mean;
    const float rstd = rsqrtf(var + 1e-12f);
    #pragma unroll
    for (int it = 0; it < 4; ++it) {
        const int idx = tid + it * 256;
        const float o = (vals[it] - mean) * rstd * g[idx] + bet[idx];
        out[(size_t)row * Ee + idx] = o;
        if (W16) out16[(size_t)row * Ee + idx] = f2bf(o);
    }
}

// ---------------------------------------------------------------------------
// Orchestration. Workspace layout (1 MB = 1<<20 bytes), 90 MB total:
//   [ 0, 8)  x16          -> later attn16 (8)         -> later inner16 head
//   [ 8,24)  rpe16        -> later ao (fp32,16)       -> (inner16 covers 8..32)
//   [24,26)  Wq_t  [26,28) Wk_t  [28,30) Wv_t  [30,32) Wr_t   (inner16 covers)
//   [32,34)  Wo_t
//   [34,42)  Wi_t
//   [42,50)  Wout_t
//   [50,58)  q16   [58,66) k16   -> later out2 (fp32, 50..66)
//   [66,74)  v16                 -> later h16 (bf16, 8)
//   [74,90)  r16                 -> later h (fp32, 16)
// ---------------------------------------------------------------------------
#define MB (1u << 20)

extern "C" void kernel_launch(void* const* d_in, const int* in_sizes, int n_in,
                              void* d_out, int out_size, void* d_ws, size_t ws_size,
                              hipStream_t stream)
{
    (void)in_sizes; (void)n_in; (void)out_size; (void)ws_size;

    const float* x    = (const float*)d_in[0];
    const float* cbf  = (const float*)d_in[1];
    const float* pbf  = (const float*)d_in[2];
    const float* rpe  = (const float*)d_in[3];
    const float* Wq   = (const float*)d_in[4];
    const float* Wk   = (const float*)d_in[5];
    const float* Wv   = (const float*)d_in[6];
    const float* Wr   = (const float*)d_in[7];
    const float* Wo   = (const float*)d_in[8];
    const float* ln1g = (const float*)d_in[9];
    const float* ln1b = (const float*)d_in[10];
    const float* Wi   = (const float*)d_in[11];
    const float* bi   = (const float*)d_in[12];
    const float* Wout = (const float*)d_in[13];
    const float* bout = (const float*)d_in[14];
    const float* ln2g = (const float*)d_in[15];
    const float* ln2b = (const float*)d_in[16];

    float* out = (float*)d_out;
    char*  ws  = (char*)d_ws;

    unsigned short* x16    = (unsigned short*)(ws + 0 * MB);
    unsigned short* rpe16  = (unsigned short*)(ws + 8 * MB);
    unsigned short* Wq_t   = (unsigned short*)(ws + 24 * MB);
    unsigned short* Wk_t   = (unsigned short*)(ws + 26 * MB);
    unsigned short* Wv_t   = (unsigned short*)(ws + 28 * MB);
    unsigned short* Wr_t   = (unsigned short*)(ws + 30 * MB);
    unsigned short* Wo_t   = (unsigned short*)(ws + 32 * MB);
    unsigned short* Wi_t   = (unsigned short*)(ws + 34 * MB);
    unsigned short* Wout_t = (unsigned short*)(ws + 42 * MB);
    unsigned short* q16    = (unsigned short*)(ws + 50 * MB);
    unsigned short* k16    = (unsigned short*)(ws + 58 * MB);
    unsigned short* v16    = (unsigned short*)(ws + 66 * MB);
    unsigned short* r16    = (unsigned short*)(ws + 74 * MB);
    unsigned short* attn16 = (unsigned short*)(ws + 0 * MB);   // reuse x16
    float*          ao     = (float*)(ws + 8 * MB);            // reuse rpe16
    unsigned short* h16    = (unsigned short*)(ws + 66 * MB);  // reuse v16
    float*          hb     = (float*)(ws + 74 * MB);           // reuse r16
    unsigned short* inner16= (unsigned short*)(ws + 0 * MB);   // 0..32 MB
    float*          out2   = (float*)(ws + 50 * MB);           // reuse q16+k16

    const dim3 blk(256);

    // Phase 1: converts + transposes
    cvt_f32_bf16<<<dim3(4096), blk, 0, stream>>>(x,   x16);    // 4,194,304 elems
    cvt_f32_bf16<<<dim3(8192), blk, 0, stream>>>(rpe, rpe16);  // 8,388,608 elems
    tr_cvt<<<dim3(32, 32),  blk, 0, stream>>>(Wq,   Wq_t,   Ee,  NHh);
    tr_cvt<<<dim3(32, 32),  blk, 0, stream>>>(Wk,   Wk_t,   Ee,  NHh);
    tr_cvt<<<dim3(32, 32),  blk, 0, stream>>>(Wv,   Wv_t,   Ee,  NHh);
    tr_cvt<<<dim3(32, 32),  blk, 0, stream>>>(Wr,   Wr_t,   Ee,  NHh);
    tr_cvt<<<dim3(32, 32),  blk, 0, stream>>>(Wo,   Wo_t,   NHh, Ee);
    tr_cvt<<<dim3(128, 32), blk, 0, stream>>>(Wi,   Wi_t,   Ee,  Ff);
    tr_cvt<<<dim3(32, 128), blk, 0, stream>>>(Wout, Wout_t, Ff,  Ee);

    // Phase 2: projections (bf16 MFMA, bf16 out)
    gemm_mfma<1,0,0><<<dim3(8, 32), blk, 0, stream>>>(x16,   Wq_t, nullptr, q16, BSs,   NHh, Ee);
    gemm_mfma<1,0,0><<<dim3(8, 32), blk, 0, stream>>>(x16,   Wk_t, nullptr, k16, BSs,   NHh, Ee);
    gemm_mfma<1,0,0><<<dim3(8, 32), blk, 0, stream>>>(x16,   Wv_t, nullptr, v16, BSs,   NHh, Ee);
    gemm_mfma<1,0,0><<<dim3(8, 64), blk, 0, stream>>>(rpe16, Wr_t, nullptr, r16, Bb*Rr, NHh, Ee);

    // Phase 3: attention
    attn_kernel<<<dim3(Ss/TM, Nn, Bb), blk, 0, stream>>>(q16, k16, v16, r16, cbf, pbf, attn16);

    // Phase 4: output projection (fp32 out)
    gemm_mfma<0,0,0><<<dim3(8, 32), blk, 0, stream>>>(attn16, Wo_t, nullptr, ao, BSs, Ee, NHh);

    // Phase 5: h = LN1(ao + x), fp32 + bf16
    add_ln_kernel<1><<<dim3(BSs), blk, 0, stream>>>(ao, x, ln1g, ln1b, hb, h16);

    // Phase 6: FFN1 (bias+relu, bf16 out)
    gemm_mfma<1,1,1><<<dim3(32, 32), blk, 0, stream>>>(h16, Wi_t, bi, inner16, BSs, Ff, Ee);

    // Phase 7: FFN2 (bias, fp32 out)
    gemm_mfma<0,1,0><<<dim3(8, 32), blk, 0, stream>>>(inner16, Wout_t, bout, out2, BSs, Ee, Ff);

    // Phase 8: out = LN2(out2 + h)
    add_ln_kernel<0><<<dim3(BSs), blk, 0, stream>>>(out2, hb, ln2g, ln2b, out, nullptr);
}

// Round 5
// 573.406 us; speedup vs baseline: 18.3721x; 2.0100x over previous
//
#include <hip/hip_runtime.h>
#include <math.h>

// Problem constants
#define Bb   4
#define Ss   1024
#define Ee   1024
#define Nn   16
#define Hh   64
#define Ff   4096
#define Rr   2048
#define NHh  1024   // N*H
#define BSs  4096   // B*S

typedef short v8s __attribute__((ext_vector_type(8)));
typedef float v4f __attribute__((ext_vector_type(4)));
typedef unsigned int u32;
typedef unsigned short us;

static __device__ inline us f2bf(float f) {
    u32 u = __builtin_bit_cast(u32, f);
    u += 0x7fffu + ((u >> 16) & 1u);   // RNE
    return (us)(u >> 16);
}
static __device__ inline float bf2f(us h) {
    u32 u = ((u32)h) << 16;
    return __builtin_bit_cast(float, u);
}
static __device__ inline void g2lds16(const void* g, void* l) {
    __builtin_amdgcn_global_load_lds(
        (const __attribute__((address_space(1))) u32*)g,
        (__attribute__((address_space(3))) u32*)l, 16, 0, 0);
}

// ---------------------------------------------------------------------------
// fp32 -> bf16 elementwise (4 elems/thread)
// ---------------------------------------------------------------------------
__global__ __launch_bounds__(256) void cvt_f32_bf16(
    const float* __restrict__ in, us* __restrict__ out)
{
    const size_t i = ((size_t)blockIdx.x * 256 + threadIdx.x) * 4;
    const float4 v = *reinterpret_cast<const float4*>(in + i);
    ushort4 o;
    o.x = f2bf(v.x); o.y = f2bf(v.y); o.z = f2bf(v.z); o.w = f2bf(v.w);
    *reinterpret_cast<ushort4*>(out + i) = o;
}

// ---------------------------------------------------------------------------
// Transpose + cvt: in [K][N] fp32 -> out [N][K] bf16. Grid (N/32, K/32).
// ---------------------------------------------------------------------------
__global__ __launch_bounds__(256) void tr_cvt(
    const float* __restrict__ in, us* __restrict__ out, int K, int N)
{
    __shared__ float t[32][33];
    const int j0 = blockIdx.x * 32, i0 = blockIdx.y * 32;
    const int r  = threadIdx.x >> 3;
    const int c4 = (threadIdx.x & 7) * 4;
    const float4 v = *reinterpret_cast<const float4*>(in + (size_t)(i0 + r) * N + j0 + c4);
    t[r][c4 + 0] = v.x; t[r][c4 + 1] = v.y; t[r][c4 + 2] = v.z; t[r][c4 + 3] = v.w;
    __syncthreads();
    ushort4 o;
    o.x = f2bf(t[c4 + 0][r]); o.y = f2bf(t[c4 + 1][r]);
    o.z = f2bf(t[c4 + 2][r]); o.w = f2bf(t[c4 + 3][r]);
    *reinterpret_cast<ushort4*>(out + (size_t)(j0 + r) * K + i0 + c4) = o;
}

// ---------------------------------------------------------------------------
// Per-(b,n) transpose of V: v16 [B,S,N,H] bf16 -> vT16 [B,N,H,S] bf16.
// Grid (S/64, B*N). 64x64 tiles through LDS.
// ---------------------------------------------------------------------------
__global__ __launch_bounds__(256) void transpose_v(
    const us* __restrict__ v16, us* __restrict__ vT16)
{
    __shared__ us T[64][72];
    const int s0 = blockIdx.x * 64;
    const int bn = blockIdx.y;          // b*16 + n
    const int b  = bn >> 4, n = bn & 15;
    const int t  = threadIdx.x;
    {
        const int r = t >> 2, c = (t & 3) * 16;
        const uint4* src = (const uint4*)(v16 + (size_t)(b * Ss + s0 + r) * NHh + n * 64 + c);
        *(uint4*)&T[r][c]     = src[0];
        *(uint4*)&T[r][c + 8] = src[1];
    }
    __syncthreads();
    {
        const int h = t >> 2, c2 = (t & 3) * 16;
        us tmp[16];
        #pragma unroll
        for (int u = 0; u < 16; ++u) tmp[u] = T[c2 + u][h];
        us* dst = vT16 + (size_t)(bn * 64 + h) * Ss + s0 + c2;
        *(uint4*)dst       = *(uint4*)tmp;
        *(uint4*)(dst + 8) = *(uint4*)(tmp + 8);
    }
}

// ---------------------------------------------------------------------------
// bf16 MFMA GEMM (m97 structure): C[M,N] = A[M,K] @ B^T  (B given as [N][K]).
// ---------------------------------------------------------------------------
template<int OUT_BF16, int BIAS, int RELU>
__global__ __launch_bounds__(256) void gemm_mfma(
    const us* __restrict__ A, const us* __restrict__ B,
    const float* __restrict__ bias, void* __restrict__ Cv,
    int M, int N, int K)
{
    __shared__ us Asm[128 * 32];
    __shared__ us Bsm[128 * 32];

    const int tid  = threadIdx.x;
    const int lane = tid & 63;
    const int wave = tid >> 6;
    const int wr   = wave >> 1, wc = wave & 1;
    const int row0 = blockIdx.y * 128, col0 = blockIdx.x * 128;
    const int lrow = lane & 15;
    const int lq   = lane >> 4;

    v4f acc[4][4];
    #pragma unroll
    for (int mt = 0; mt < 4; ++mt)
        #pragma unroll
        for (int nt = 0; nt < 4; ++nt)
            acc[mt][nt] = (v4f){0.f, 0.f, 0.f, 0.f};

    const int ca = tid, cb2 = tid + 256;
    const int ra = ca >> 2,  ka = (ca & 3) * 8;
    const int rb = cb2 >> 2, kb = (cb2 & 3) * 8;

    for (int k0 = 0; k0 < K; k0 += 32) {
        g2lds16(A + (size_t)(row0 + ra) * K + k0 + ka, &Asm[ca * 8]);
        g2lds16(A + (size_t)(row0 + rb) * K + k0 + kb, &Asm[cb2 * 8]);
        g2lds16(B + (size_t)(col0 + ra) * K + k0 + ka, &Bsm[ca * 8]);
        g2lds16(B + (size_t)(col0 + rb) * K + k0 + kb, &Bsm[cb2 * 8]);
        __syncthreads();

        v8s af[4], bf[4];
        #pragma unroll
        for (int mt = 0; mt < 4; ++mt)
            af[mt] = *reinterpret_cast<const v8s*>(&Asm[(wr * 64 + mt * 16 + lrow) * 32 + lq * 8]);
        #pragma unroll
        for (int nt = 0; nt < 4; ++nt)
            bf[nt] = *reinterpret_cast<const v8s*>(&Bsm[(wc * 64 + nt * 16 + lrow) * 32 + lq * 8]);
        #pragma unroll
        for (int mt = 0; mt < 4; ++mt)
            #pragma unroll
            for (int nt = 0; nt < 4; ++nt)
                acc[mt][nt] = __builtin_amdgcn_mfma_f32_16x16x32_bf16(
                    af[mt], bf[nt], acc[mt][nt], 0, 0, 0);
        __syncthreads();
    }

    #pragma unroll
    for (int nt = 0; nt < 4; ++nt) {
        const int col = col0 + wc * 64 + nt * 16 + lrow;
        const float bv = BIAS ? bias[col] : 0.f;
        #pragma unroll
        for (int mt = 0; mt < 4; ++mt) {
            #pragma unroll
            for (int v = 0; v < 4; ++v) {
                const int row = row0 + wr * 64 + mt * 16 + lq * 4 + v;
                float val = acc[mt][nt][v] + bv;
                if (RELU) val = fmaxf(val, 0.f);
                if (OUT_BF16)
                    ((us*)Cv)[(size_t)row * N + col] = f2bf(val);
                else
                    ((float*)Cv)[(size_t)row * N + col] = val;
            }
        }
    }
}

// ---------------------------------------------------------------------------
// MFMA flash attention with rel-shift ring buffer.
// Block = (64-query tile i0, n, b), 256 thr / 4 waves; 16 key-tiles of 64.
// Content scores: qc(regs) x Kt(LDS) MFMA. Pos scores: qp x Rt chunk MFMA ->
// bf16 ring[i][l&127] (wave-private rows); score read gathers ring at
// l = j + S - i (rel-shift folded; scale 0.125 pre-folded into qc/qp).
// No online max (|s| bounded ~4): p = exp(s), deferred row-sum.
// P -> LDS bf16 -> A-frag; V pre-transposed so PV B-frags are b128 reads.
// ---------------------------------------------------------------------------
#define QP 72     // pitch for qc/qp/Kt/Rt/VtT/Pt tiles (bank spread 4)
#define RINGP 132 // ring pitch

__global__ __launch_bounds__(256) void attn_mfma(
    const us* __restrict__ q16, const us* __restrict__ k16,
    const us* __restrict__ vT16, const us* __restrict__ r16,
    const float* __restrict__ cb, const float* __restrict__ pb,
    us* __restrict__ attn)
{
    __shared__ __align__(16) char smem[53760];
    us* qcS  = (us*)smem;              // prologue only
    us* qpS  = (us*)(smem + 9216);     // prologue only
    us* Kt   = (us*)smem;              // main loop (overlays qcS)
    us* Rt   = (us*)(smem + 9216);     // main loop (overlays qpS)
    us* VtT  = (us*)(smem + 18432);
    us* ring = (us*)(smem + 27648);    // 64 x 132 bf16
    us* Pt   = (us*)(smem + 44544);    // 64 x 72 bf16

    const int i0 = blockIdx.x * 64;
    const int n  = blockIdx.y;
    const int b  = blockIdx.z;
    const int tid  = threadIdx.x;
    const int lane = tid & 63;
    const int w    = tid >> 6;
    const int quad = lane >> 4;
    const int l15  = lane & 15;
    const int w16  = w * 16;

    // ---- Prologue: stage qc = (q+cb)*0.125, qp = (q+pb)*0.125 (bf16) ----
    {
        const int r = tid >> 2, c = (tid & 3) * 16;
        const uint4* src = (const uint4*)(q16 + (size_t)(b * Ss + i0 + r) * NHh + n * 64 + c);
        uint4 qa = src[0], qb = src[1];
        us qs[16];
        *(uint4*)qs       = qa;
        *(uint4*)(qs + 8) = qb;
        const float* cbp = cb + n * 64 + c;
        const float* pbp = pb + n * 64 + c;
        us oc[16], op[16];
        #pragma unroll
        for (int u = 0; u < 16; ++u) {
            const float qf = bf2f(qs[u]);
            oc[u] = f2bf((qf + cbp[u]) * 0.125f);
            op[u] = f2bf((qf + pbp[u]) * 0.125f);
        }
        *(uint4*)&qcS[r * QP + c]     = *(uint4*)oc;
        *(uint4*)&qcS[r * QP + c + 8] = *(uint4*)(oc + 8);
        *(uint4*)&qpS[r * QP + c]     = *(uint4*)op;
        *(uint4*)&qpS[r * QP + c + 8] = *(uint4*)(op + 8);
    }
    __syncthreads();

    // A-fragments in registers (wave w owns queries [w16, w16+16))
    v8s aqc0 = *(v8s*)&qcS[(w16 + l15) * QP + quad * 8];
    v8s aqc1 = *(v8s*)&qcS[(w16 + l15) * QP + 32 + quad * 8];
    v8s aqp0 = *(v8s*)&qpS[(w16 + l15) * QP + quad * 8];
    v8s aqp1 = *(v8s*)&qpS[(w16 + l15) * QP + 32 + quad * 8];
    __syncthreads();   // all reads done before Kt/Rt overlay

    const int c0 = Ss - i0;   // l at j-i diag base

    // ---- Bootstrap: pos chunk l in [c0-64, c0) ----
    {
        const int lbase = c0 - 64;
        const int r = tid >> 2, c = (tid & 3) * 16;
        const uint4* src = (const uint4*)(r16 + (size_t)(b * Rr + lbase + r) * NHh + n * 64 + c);
        *(uint4*)&Rt[r * QP + c]     = src[0];
        *(uint4*)&Rt[r * QP + c + 8] = src[1];
        __syncthreads();
        const v4f z = (v4f){0.f, 0.f, 0.f, 0.f};
        #pragma unroll
        for (int t = 0; t < 4; ++t) {
            v8s br0 = *(v8s*)&Rt[(t * 16 + l15) * QP + quad * 8];
            v8s br1 = *(v8s*)&Rt[(t * 16 + l15) * QP + 32 + quad * 8];
            v4f pp = __builtin_amdgcn_mfma_f32_16x16x32_bf16(aqp0, br0, z, 0, 0, 0);
            pp = __builtin_amdgcn_mfma_f32_16x16x32_bf16(aqp1, br1, pp, 0, 0, 0);
            #pragma unroll
            for (int v = 0; v < 4; ++v)
                ring[(w16 + quad * 4 + v) * RINGP + ((lbase + t * 16 + l15) & 127)] = f2bf(pp[v]);
        }
    }

    v4f Oa[4];
    #pragma unroll
    for (int t = 0; t < 4; ++t) Oa[t] = (v4f){0.f, 0.f, 0.f, 0.f};
    float la[4] = {0.f, 0.f, 0.f, 0.f};

    // ---- Main flash loop over key tiles ----
    for (int j0 = 0; j0 < Ss; j0 += 64) {
        __syncthreads();   // prev iter LDS reads done (also covers bootstrap Rt)
        {
            const int r = tid >> 2, c = (tid & 3) * 16;
            const int lbase = j0 + c0;
            const uint4* sk = (const uint4*)(k16 + (size_t)(b * Ss + j0 + r) * NHh + n * 64 + c);
            const uint4* sr = (const uint4*)(r16 + (size_t)(b * Rr + lbase + r) * NHh + n * 64 + c);
            const uint4* sv = (const uint4*)(vT16 + (size_t)((b * 16 + n) * 64 + r) * Ss + j0 + c);
            uint4 k0v = sk[0], k1v = sk[1];
            uint4 r0v = sr[0], r1v = sr[1];
            uint4 v0v = sv[0], v1v = sv[1];
            *(uint4*)&Kt[r * QP + c]      = k0v;
            *(uint4*)&Kt[r * QP + c + 8]  = k1v;
            *(uint4*)&Rt[r * QP + c]      = r0v;
            *(uint4*)&Rt[r * QP + c + 8]  = r1v;
            *(uint4*)&VtT[r * QP + c]     = v0v;
            *(uint4*)&VtT[r * QP + c + 8] = v1v;
        }
        __syncthreads();

        const v4f z = (v4f){0.f, 0.f, 0.f, 0.f};
        // Content scores + pos chunk
        v4f sc[4];
        #pragma unroll
        for (int t = 0; t < 4; ++t) {
            v8s bk0 = *(v8s*)&Kt[(t * 16 + l15) * QP + quad * 8];
            v8s bk1 = *(v8s*)&Kt[(t * 16 + l15) * QP + 32 + quad * 8];
            sc[t] = __builtin_amdgcn_mfma_f32_16x16x32_bf16(aqc0, bk0, z, 0, 0, 0);
            sc[t] = __builtin_amdgcn_mfma_f32_16x16x32_bf16(aqc1, bk1, sc[t], 0, 0, 0);
        }
        const int lbase = j0 + c0;
        #pragma unroll
        for (int t = 0; t < 4; ++t) {
            v8s br0 = *(v8s*)&Rt[(t * 16 + l15) * QP + quad * 8];
            v8s br1 = *(v8s*)&Rt[(t * 16 + l15) * QP + 32 + quad * 8];
            v4f pp = __builtin_amdgcn_mfma_f32_16x16x32_bf16(aqp0, br0, z, 0, 0, 0);
            pp = __builtin_amdgcn_mfma_f32_16x16x32_bf16(aqp1, br1, pp, 0, 0, 0);
            #pragma unroll
            for (int v = 0; v < 4; ++v)
                ring[(w16 + quad * 4 + v) * RINGP + ((lbase + t * 16 + l15) & 127)] = f2bf(pp[v]);
        }

        // Scores -> exp -> Pt (wave-private rows; same-wave LDS dep in-order)
        #pragma unroll
        for (int t = 0; t < 4; ++t) {
            #pragma unroll
            for (int v = 0; v < 4; ++v) {
                const int irow = w16 + quad * 4 + v;
                const int l = (j0 + t * 16 + l15) + Ss - (i0 + irow);
                const float pos = bf2f(ring[irow * RINGP + (l & 127)]);
                const float p = __expf(sc[t][v] + pos);
                la[v] += p;
                Pt[irow * QP + t * 16 + l15] = f2bf(p);
            }
        }

        // PV
        v8s pa0 = *(v8s*)&Pt[(w16 + l15) * QP + quad * 8];
        v8s pa1 = *(v8s*)&Pt[(w16 + l15) * QP + 32 + quad * 8];
        #pragma unroll
        for (int ht = 0; ht < 4; ++ht) {
            v8s bv0 = *(v8s*)&VtT[(ht * 16 + l15) * QP + quad * 8];
            v8s bv1 = *(v8s*)&VtT[(ht * 16 + l15) * QP + 32 + quad * 8];
            Oa[ht] = __builtin_amdgcn_mfma_f32_16x16x32_bf16(pa0, bv0, Oa[ht], 0, 0, 0);
            Oa[ht] = __builtin_amdgcn_mfma_f32_16x16x32_bf16(pa1, bv1, Oa[ht], 0, 0, 0);
        }
    }

    // ---- Epilogue: reduce row sums across quad, normalize, store ----
    #pragma unroll
    for (int v = 0; v < 4; ++v) {
        la[v] += __shfl_xor(la[v], 1);
        la[v] += __shfl_xor(la[v], 2);
        la[v] += __shfl_xor(la[v], 4);
        la[v] += __shfl_xor(la[v], 8);
        la[v] = 1.f / la[v];
    }
    #pragma unroll
    for (int ht = 0; ht < 4; ++ht) {
        #pragma unroll
        for (int v = 0; v < 4; ++v) {
            const int irow = w16 + quad * 4 + v;
            attn[(size_t)(b * Ss + i0 + irow) * NHh + n * 64 + ht * 16 + l15] =
                f2bf(Oa[ht][v] * la[v]);
        }
    }
}

// ---------------------------------------------------------------------------
// Fused residual-add + LayerNorm over E=1024; optional bf16 copy of output.
// ---------------------------------------------------------------------------
template<int W16>
__global__ __launch_bounds__(256) void add_ln_kernel(
    const float* __restrict__ a, const float* __restrict__ res,
    const float* __restrict__ g, const float* __restrict__ bet,
    float* __restrict__ out, us* __restrict__ out16)
{
    const int row = blockIdx.x;
    const int tid = threadIdx.x;
    const float* ar = a   + (size_t)row * Ee;
    const float* rr = res + (size_t)row * Ee;

    float vals[4];
    float lsum = 0.f, lsq = 0.f;
    #pragma unroll
    for (int it = 0; it < 4; ++it) {
        const int idx = tid + it * 256;
        const float vv = ar[idx] + rr[idx];
        vals[it] = vv;
        lsum += vv;
        lsq  = fmaf(vv, vv, lsq);
    }
    #pragma unroll
    for (int off = 32; off > 0; off >>= 1) {
        lsum += __shfl_down(lsum, off);
        lsq  += __shfl_down(lsq,  off);
    }
    __shared__ float w1[4], w2[4];
    if ((tid & 63) == 0) { w1[tid >> 6] = lsum; w2[tid >> 6] = lsq; }
    __syncthreads();
    const float sum  = w1[0] + w1[1] + w1[2] + w1[3];
    const float sq   = w2[0] + w2[1] + w2[2] + w2[3];
    const float mean = sum * (1.f / 1024.f);
    const float var  = sq * (1.f / 1024.f) - mean * mean;
    const float rstd = rsqrtf(var + 1e-12f);
    #pragma unroll
    for (int it = 0; it < 4; ++it) {
        const int idx = tid + it * 256;
        const float o = (vals[it] - mean) * rstd * g[idx] + bet[idx];
        out[(size_t)row * Ee + idx] = o;
        if (W16) out16[(size_t)row * Ee + idx] = f2bf(o);
    }
}

// ---------------------------------------------------------------------------
// Orchestration. Workspace layout (1 MB units), 90 MB total:
//   [ 0, 8)  x16        -> attn16 (phase 3)  -> inner16 head (phase 6)
//   [ 8,24)  rpe16      -> vT16 [8,16) (phase 2.5)  -> ao fp32 (phase 4)
//   [24,34)  weight transposes Wq/Wk/Wv/Wr/Wo  (inner16 covers 24..32)
//   [34,42)  Wi_t   [42,50) Wout_t
//   [50,58)  q16    [58,66) k16    -> out2 fp32 [50,66) (phase 7)
//   [66,74)  v16    -> h16 (phase 5)
//   [74,90)  r16    -> hb fp32 (phase 5; r16 last read in phase 3)
// ---------------------------------------------------------------------------
#define MB (1u << 20)

extern "C" void kernel_launch(void* const* d_in, const int* in_sizes, int n_in,
                              void* d_out, int out_size, void* d_ws, size_t ws_size,
                              hipStream_t stream)
{
    (void)in_sizes; (void)n_in; (void)out_size; (void)ws_size;

    const float* x    = (const float*)d_in[0];
    const float* cbf  = (const float*)d_in[1];
    const float* pbf  = (const float*)d_in[2];
    const float* rpe  = (const float*)d_in[3];
    const float* Wq   = (const float*)d_in[4];
    const float* Wk   = (const float*)d_in[5];
    const float* Wv   = (const float*)d_in[6];
    const float* Wr   = (const float*)d_in[7];
    const float* Wo   = (const float*)d_in[8];
    const float* ln1g = (const float*)d_in[9];
    const float* ln1b = (const float*)d_in[10];
    const float* Wi   = (const float*)d_in[11];
    const float* bi   = (const float*)d_in[12];
    const float* Wout = (const float*)d_in[13];
    const float* bout = (const float*)d_in[14];
    const float* ln2g = (const float*)d_in[15];
    const float* ln2b = (const float*)d_in[16];

    float* out = (float*)d_out;
    char*  ws  = (char*)d_ws;

    us* x16    = (us*)(ws + 0 * MB);
    us* rpe16  = (us*)(ws + 8 * MB);
    us* Wq_t   = (us*)(ws + 24 * MB);
    us* Wk_t   = (us*)(ws + 26 * MB);
    us* Wv_t   = (us*)(ws + 28 * MB);
    us* Wr_t   = (us*)(ws + 30 * MB);
    us* Wo_t   = (us*)(ws + 32 * MB);
    us* Wi_t   = (us*)(ws + 34 * MB);
    us* Wout_t = (us*)(ws + 42 * MB);
    us* q16    = (us*)(ws + 50 * MB);
    us* k16    = (us*)(ws + 58 * MB);
    us* v16    = (us*)(ws + 66 * MB);
    us* r16    = (us*)(ws + 74 * MB);
    us* attn16 = (us*)(ws + 0 * MB);   // reuse x16
    us* vT16   = (us*)(ws + 8 * MB);   // reuse rpe16 (after phase 2)
    float* ao  = (float*)(ws + 8 * MB);// reuse vT16 (after attn)
    us* h16    = (us*)(ws + 66 * MB);  // reuse v16
    float* hb  = (float*)(ws + 74 * MB); // reuse r16 (after attn)
    us* inner16= (us*)(ws + 0 * MB);   // 0..32 MB
    float* out2= (float*)(ws + 50 * MB);

    const dim3 blk(256);

    // Phase 1: converts + transposes
    cvt_f32_bf16<<<dim3(4096), blk, 0, stream>>>(x,   x16);
    cvt_f32_bf16<<<dim3(8192), blk, 0, stream>>>(rpe, rpe16);
    tr_cvt<<<dim3(32, 32),  blk, 0, stream>>>(Wq,   Wq_t,   Ee,  NHh);
    tr_cvt<<<dim3(32, 32),  blk, 0, stream>>>(Wk,   Wk_t,   Ee,  NHh);
    tr_cvt<<<dim3(32, 32),  blk, 0, stream>>>(Wv,   Wv_t,   Ee,  NHh);
    tr_cvt<<<dim3(32, 32),  blk, 0, stream>>>(Wr,   Wr_t,   Ee,  NHh);
    tr_cvt<<<dim3(32, 32),  blk, 0, stream>>>(Wo,   Wo_t,   NHh, Ee);
    tr_cvt<<<dim3(128, 32), blk, 0, stream>>>(Wi,   Wi_t,   Ee,  Ff);
    tr_cvt<<<dim3(32, 128), blk, 0, stream>>>(Wout, Wout_t, Ff,  Ee);

    // Phase 2: projections
    gemm_mfma<1,0,0><<<dim3(8, 32), blk, 0, stream>>>(x16,   Wq_t, nullptr, q16, BSs,   NHh, Ee);
    gemm_mfma<1,0,0><<<dim3(8, 32), blk, 0, stream>>>(x16,   Wk_t, nullptr, k16, BSs,   NHh, Ee);
    gemm_mfma<1,0,0><<<dim3(8, 32), blk, 0, stream>>>(x16,   Wv_t, nullptr, v16, BSs,   NHh, Ee);
    gemm_mfma<1,0,0><<<dim3(8, 64), blk, 0, stream>>>(rpe16, Wr_t, nullptr, r16, Bb*Rr, NHh, Ee);

    // Phase 2.5: V transpose [B,S,N,H] -> [B,N,H,S]
    transpose_v<<<dim3(16, 64), blk, 0, stream>>>(v16, vT16);

    // Phase 3: MFMA flash attention
    attn_mfma<<<dim3(16, Nn, Bb), blk, 0, stream>>>(q16, k16, vT16, r16, cbf, pbf, attn16);

    // Phase 4: output projection (fp32 out)
    gemm_mfma<0,0,0><<<dim3(8, 32), blk, 0, stream>>>(attn16, Wo_t, nullptr, ao, BSs, Ee, NHh);

    // Phase 5: h = LN1(ao + x), fp32 + bf16
    add_ln_kernel<1><<<dim3(BSs), blk, 0, stream>>>(ao, x, ln1g, ln1b, hb, h16);

    // Phase 6: FFN1 (bias+relu, bf16 out)
    gemm_mfma<1,1,1><<<dim3(32, 32), blk, 0, stream>>>(h16, Wi_t, bi, inner16, BSs, Ff, Ee);

    // Phase 7: FFN2 (bias, fp32 out)
    gemm_mfma<0,1,0><<<dim3(8, 32), blk, 0, stream>>>(inner16, Wout_t, bout, out2, BSs, Ee, Ff);

    // Phase 8: out = LN2(out2 + h)
    add_ln_kernel<0><<<dim3(BSs), blk, 0, stream>>>(out2, hb, ln2g, ln2b, out, nullptr);
}

// Round 6
// 529.810 us; speedup vs baseline: 19.8839x; 1.0823x over previous
//
#include <hip/hip_runtime.h>
#include <math.h>

// Problem constants
#define Bb   4
#define Ss   1024
#define Ee   1024
#define Nn   16
#define Hh   64
#define Ff   4096
#define Rr   2048
#define NHh  1024   // N*H
#define BSs  4096   // B*S
#define QKVLD 3072  // fused qkv row stride

typedef short v8s __attribute__((ext_vector_type(8)));
typedef float v4f __attribute__((ext_vector_type(4)));
typedef unsigned int u32;
typedef unsigned short us;

static __device__ inline us f2bf(float f) {
    u32 u = __builtin_bit_cast(u32, f);
    u += 0x7fffu + ((u >> 16) & 1u);   // RNE
    return (us)(u >> 16);
}
static __device__ inline float bf2f(us h) {
    u32 u = ((u32)h) << 16;
    return __builtin_bit_cast(float, u);
}
static __device__ inline void g2lds16(const void* g, void* l) {
    __builtin_amdgcn_global_load_lds(
        (const __attribute__((address_space(1))) u32*)g,
        (__attribute__((address_space(3))) u32*)l, 16, 0, 0);
}

// ---------------------------------------------------------------------------
// fp32 -> bf16 elementwise (4 elems/thread)
// ---------------------------------------------------------------------------
__global__ __launch_bounds__(256) void cvt_f32_bf16(
    const float* __restrict__ in, us* __restrict__ out)
{
    const size_t i = ((size_t)blockIdx.x * 256 + threadIdx.x) * 4;
    const float4 v = *reinterpret_cast<const float4*>(in + i);
    ushort4 o;
    o.x = f2bf(v.x); o.y = f2bf(v.y); o.z = f2bf(v.z); o.w = f2bf(v.w);
    *reinterpret_cast<ushort4*>(out + i) = o;
}

// ---------------------------------------------------------------------------
// Transpose + cvt: in [K][N] fp32 -> out [N][K] bf16. Grid (N/32, K/32).
// ---------------------------------------------------------------------------
__global__ __launch_bounds__(256) void tr_cvt(
    const float* __restrict__ in, us* __restrict__ out, int K, int N)
{
    __shared__ float t[32][33];
    const int j0 = blockIdx.x * 32, i0 = blockIdx.y * 32;
    const int r  = threadIdx.x >> 3;
    const int c4 = (threadIdx.x & 7) * 4;
    const float4 v = *reinterpret_cast<const float4*>(in + (size_t)(i0 + r) * N + j0 + c4);
    t[r][c4 + 0] = v.x; t[r][c4 + 1] = v.y; t[r][c4 + 2] = v.z; t[r][c4 + 3] = v.w;
    __syncthreads();
    ushort4 o;
    o.x = f2bf(t[c4 + 0][r]); o.y = f2bf(t[c4 + 1][r]);
    o.z = f2bf(t[c4 + 2][r]); o.w = f2bf(t[c4 + 3][r]);
    *reinterpret_cast<ushort4*>(out + (size_t)(j0 + r) * K + i0 + c4) = o;
}

// ---------------------------------------------------------------------------
// Per-(b,n) transpose of V: v16 (stride ld) [B,S,*] -> vT16 [B,N,H,S] bf16.
// Grid (S/64, B*N). 64x64 tiles through LDS.
// ---------------------------------------------------------------------------
__global__ __launch_bounds__(256) void transpose_v(
    const us* __restrict__ v16, us* __restrict__ vT16, int ld)
{
    __shared__ us T[64][72];
    const int s0 = blockIdx.x * 64;
    const int bn = blockIdx.y;          // b*16 + n
    const int b  = bn >> 4, n = bn & 15;
    const int t  = threadIdx.x;
    {
        const int r = t >> 2, c = (t & 3) * 16;
        const uint4* src = (const uint4*)(v16 + (size_t)(b * Ss + s0 + r) * ld + n * 64 + c);
        *(uint4*)&T[r][c]     = src[0];
        *(uint4*)&T[r][c + 8] = src[1];
    }
    __syncthreads();
    {
        const int h = t >> 2, c2 = (t & 3) * 16;
        us tmp[16];
        #pragma unroll
        for (int u = 0; u < 16; ++u) tmp[u] = T[c2 + u][h];
        us* dst = vT16 + (size_t)(bn * 64 + h) * Ss + s0 + c2;
        *(uint4*)dst       = *(uint4*)tmp;
        *(uint4*)(dst + 8) = *(uint4*)(tmp + 8);
    }
}

// ---------------------------------------------------------------------------
// bf16 MFMA GEMM (m97 structure + XOR-swizzled LDS): C = A[M,K] @ B^T.
// 128x128 tile, BK=32, 4 waves 2x2, 4x4 of 16x16x32 each.
// Swizzle: LDS slot s holds global chunk (row=s>>2, kc=(s&3)^((s>>3)&3));
// fragment read for (row,lq) hits slot row*4 + (lq ^ ((row>>1)&3)).
// -> 2 lanes/bank (free) instead of 8-way conflicts.
// ---------------------------------------------------------------------------
template<int OUT_BF16, int BIAS, int RELU>
__global__ __launch_bounds__(256) void gemm_mfma(
    const us* __restrict__ A, const us* __restrict__ B,
    const float* __restrict__ bias, void* __restrict__ Cv,
    int M, int N, int K, int ldC)
{
    __shared__ us Asm[128 * 32];
    __shared__ us Bsm[128 * 32];

    const int tid  = threadIdx.x;
    const int lane = tid & 63;
    const int wave = tid >> 6;
    const int wr   = wave >> 1, wc = wave & 1;
    const int row0 = blockIdx.y * 128, col0 = blockIdx.x * 128;
    const int lrow = lane & 15;
    const int lq   = lane >> 4;
    const int xsw  = (lrow >> 1) & 3;          // fragment-read swizzle
    const int kq0  = (lq ^ xsw) * 8;

    v4f acc[4][4];
    #pragma unroll
    for (int mt = 0; mt < 4; ++mt)
        #pragma unroll
        for (int nt = 0; nt < 4; ++nt)
            acc[mt][nt] = (v4f){0.f, 0.f, 0.f, 0.f};

    // staging: lane tid fills slots tid and tid+256; source chunk swizzled
    const int ra = tid >> 2;
    const int kc = ((tid & 3) ^ ((tid >> 3) & 3)) * 8;

    for (int k0 = 0; k0 < K; k0 += 32) {
        g2lds16(A + (size_t)(row0 + ra) * K + k0 + kc,      &Asm[tid * 8]);
        g2lds16(A + (size_t)(row0 + 64 + ra) * K + k0 + kc, &Asm[(tid + 256) * 8]);
        g2lds16(B + (size_t)(col0 + ra) * K + k0 + kc,      &Bsm[tid * 8]);
        g2lds16(B + (size_t)(col0 + 64 + ra) * K + k0 + kc, &Bsm[(tid + 256) * 8]);
        __syncthreads();

        v8s af[4], bf[4];
        #pragma unroll
        for (int mt = 0; mt < 4; ++mt)
            af[mt] = *reinterpret_cast<const v8s*>(&Asm[(wr * 64 + mt * 16 + lrow) * 32 + kq0]);
        #pragma unroll
        for (int nt = 0; nt < 4; ++nt)
            bf[nt] = *reinterpret_cast<const v8s*>(&Bsm[(wc * 64 + nt * 16 + lrow) * 32 + kq0]);
        #pragma unroll
        for (int mt = 0; mt < 4; ++mt)
            #pragma unroll
            for (int nt = 0; nt < 4; ++nt)
                acc[mt][nt] = __builtin_amdgcn_mfma_f32_16x16x32_bf16(
                    af[mt], bf[nt], acc[mt][nt], 0, 0, 0);
        __syncthreads();
    }

    #pragma unroll
    for (int nt = 0; nt < 4; ++nt) {
        const int col = col0 + wc * 64 + nt * 16 + lrow;
        const float bv = BIAS ? bias[col] : 0.f;
        #pragma unroll
        for (int mt = 0; mt < 4; ++mt) {
            #pragma unroll
            for (int v = 0; v < 4; ++v) {
                const int row = row0 + wr * 64 + mt * 16 + (lane >> 4) * 4 + v;
                float val = acc[mt][nt][v] + bv;
                if (RELU) val = fmaxf(val, 0.f);
                if (OUT_BF16)
                    ((us*)Cv)[(size_t)row * ldC + col] = f2bf(val);
                else
                    ((float*)Cv)[(size_t)row * ldC + col] = val;
            }
        }
    }
}

// ---------------------------------------------------------------------------
// MFMA flash attention with rel-shift ring buffer (see R3/R4 notes).
// LDS shrunk to 52,992 B -> 3 blocks/CU. q/k read from fused qkv (ld 3072).
// ---------------------------------------------------------------------------
#define QP 72      // pitch for qc/qp/Kt/Rt/VtT
#define PTP 68     // Pt pitch
#define RINGP 130  // ring pitch

__global__ __launch_bounds__(256) void attn_mfma(
    const us* __restrict__ qkv, const us* __restrict__ vT16,
    const us* __restrict__ r16,
    const float* __restrict__ cb, const float* __restrict__ pb,
    us* __restrict__ attn)
{
    __shared__ __align__(16) char smem[52992];
    us* qcS  = (us*)smem;              // prologue only
    us* qpS  = (us*)(smem + 9216);     // prologue only
    us* Kt   = (us*)smem;              // main loop (overlays qcS)
    us* Rt   = (us*)(smem + 9216);     // main loop (overlays qpS)
    us* VtT  = (us*)(smem + 18432);
    us* ring = (us*)(smem + 27648);    // 64 x 130 bf16
    us* Pt   = (us*)(smem + 44288);    // 64 x 68 bf16

    const int i0 = blockIdx.x * 64;
    const int n  = blockIdx.y;
    const int b  = blockIdx.z;
    const int tid  = threadIdx.x;
    const int lane = tid & 63;
    const int w    = tid >> 6;
    const int quad = lane >> 4;
    const int l15  = lane & 15;
    const int w16  = w * 16;

    // ---- Prologue: stage qc = (q+cb)*0.125, qp = (q+pb)*0.125 (bf16) ----
    {
        const int r = tid >> 2, c = (tid & 3) * 16;
        const uint4* src = (const uint4*)(qkv + (size_t)(b * Ss + i0 + r) * QKVLD + n * 64 + c);
        uint4 qa = src[0], qb = src[1];
        us qs[16];
        *(uint4*)qs       = qa;
        *(uint4*)(qs + 8) = qb;
        const float* cbp = cb + n * 64 + c;
        const float* pbp = pb + n * 64 + c;
        us oc[16], op[16];
        #pragma unroll
        for (int u = 0; u < 16; ++u) {
            const float qf = bf2f(qs[u]);
            oc[u] = f2bf((qf + cbp[u]) * 0.125f);
            op[u] = f2bf((qf + pbp[u]) * 0.125f);
        }
        *(uint4*)&qcS[r * QP + c]     = *(uint4*)oc;
        *(uint4*)&qcS[r * QP + c + 8] = *(uint4*)(oc + 8);
        *(uint4*)&qpS[r * QP + c]     = *(uint4*)op;
        *(uint4*)&qpS[r * QP + c + 8] = *(uint4*)(op + 8);
    }
    __syncthreads();

    // A-fragments in registers (wave w owns queries [w16, w16+16))
    v8s aqc0 = *(v8s*)&qcS[(w16 + l15) * QP + quad * 8];
    v8s aqc1 = *(v8s*)&qcS[(w16 + l15) * QP + 32 + quad * 8];
    v8s aqp0 = *(v8s*)&qpS[(w16 + l15) * QP + quad * 8];
    v8s aqp1 = *(v8s*)&qpS[(w16 + l15) * QP + 32 + quad * 8];
    __syncthreads();   // all reads done before Kt/Rt overlay

    const int c0 = Ss - i0;   // l at j-i diag base

    // ---- Bootstrap: pos chunk l in [c0-64, c0) ----
    {
        const int lbase = c0 - 64;
        const int r = tid >> 2, c = (tid & 3) * 16;
        const uint4* src = (const uint4*)(r16 + (size_t)(b * Rr + lbase + r) * NHh + n * 64 + c);
        *(uint4*)&Rt[r * QP + c]     = src[0];
        *(uint4*)&Rt[r * QP + c + 8] = src[1];
        __syncthreads();
        const v4f z = (v4f){0.f, 0.f, 0.f, 0.f};
        #pragma unroll
        for (int t = 0; t < 4; ++t) {
            v8s br0 = *(v8s*)&Rt[(t * 16 + l15) * QP + quad * 8];
            v8s br1 = *(v8s*)&Rt[(t * 16 + l15) * QP + 32 + quad * 8];
            v4f pp = __builtin_amdgcn_mfma_f32_16x16x32_bf16(aqp0, br0, z, 0, 0, 0);
            pp = __builtin_amdgcn_mfma_f32_16x16x32_bf16(aqp1, br1, pp, 0, 0, 0);
            #pragma unroll
            for (int v = 0; v < 4; ++v)
                ring[(w16 + quad * 4 + v) * RINGP + ((lbase + t * 16 + l15) & 127)] = f2bf(pp[v]);
        }
    }

    v4f Oa[4];
    #pragma unroll
    for (int t = 0; t < 4; ++t) Oa[t] = (v4f){0.f, 0.f, 0.f, 0.f};
    float la[4] = {0.f, 0.f, 0.f, 0.f};

    // ---- Main flash loop over key tiles ----
    for (int j0 = 0; j0 < Ss; j0 += 64) {
        __syncthreads();   // prev iter LDS reads done
        {
            const int r = tid >> 2, c = (tid & 3) * 16;
            const int lbase = j0 + c0;
            const uint4* sk = (const uint4*)(qkv + (size_t)(b * Ss + j0 + r) * QKVLD + NHh + n * 64 + c);
            const uint4* sr = (const uint4*)(r16 + (size_t)(b * Rr + lbase + r) * NHh + n * 64 + c);
            const uint4* sv = (const uint4*)(vT16 + (size_t)((b * 16 + n) * 64 + r) * Ss + j0 + c);
            uint4 k0v = sk[0], k1v = sk[1];
            uint4 r0v = sr[0], r1v = sr[1];
            uint4 v0v = sv[0], v1v = sv[1];
            *(uint4*)&Kt[r * QP + c]      = k0v;
            *(uint4*)&Kt[r * QP + c + 8]  = k1v;
            *(uint4*)&Rt[r * QP + c]      = r0v;
            *(uint4*)&Rt[r * QP + c + 8]  = r1v;
            *(uint4*)&VtT[r * QP + c]     = v0v;
            *(uint4*)&VtT[r * QP + c + 8] = v1v;
        }
        __syncthreads();

        const v4f z = (v4f){0.f, 0.f, 0.f, 0.f};
        // Content scores + pos chunk
        v4f sc[4];
        #pragma unroll
        for (int t = 0; t < 4; ++t) {
            v8s bk0 = *(v8s*)&Kt[(t * 16 + l15) * QP + quad * 8];
            v8s bk1 = *(v8s*)&Kt[(t * 16 + l15) * QP + 32 + quad * 8];
            sc[t] = __builtin_amdgcn_mfma_f32_16x16x32_bf16(aqc0, bk0, z, 0, 0, 0);
            sc[t] = __builtin_amdgcn_mfma_f32_16x16x32_bf16(aqc1, bk1, sc[t], 0, 0, 0);
        }
        const int lbase = j0 + c0;
        #pragma unroll
        for (int t = 0; t < 4; ++t) {
            v8s br0 = *(v8s*)&Rt[(t * 16 + l15) * QP + quad * 8];
            v8s br1 = *(v8s*)&Rt[(t * 16 + l15) * QP + 32 + quad * 8];
            v4f pp = __builtin_amdgcn_mfma_f32_16x16x32_bf16(aqp0, br0, z, 0, 0, 0);
            pp = __builtin_amdgcn_mfma_f32_16x16x32_bf16(aqp1, br1, pp, 0, 0, 0);
            #pragma unroll
            for (int v = 0; v < 4; ++v)
                ring[(w16 + quad * 4 + v) * RINGP + ((lbase + t * 16 + l15) & 127)] = f2bf(pp[v]);
        }

        // Scores -> exp -> Pt (wave-private rows; same-wave LDS dep in-order)
        #pragma unroll
        for (int t = 0; t < 4; ++t) {
            #pragma unroll
            for (int v = 0; v < 4; ++v) {
                const int irow = w16 + quad * 4 + v;
                const int l = (j0 + t * 16 + l15) + Ss - (i0 + irow);
                const float pos = bf2f(ring[irow * RINGP + (l & 127)]);
                const float p = __expf(sc[t][v] + pos);
                la[v] += p;
                Pt[irow * PTP + t * 16 + l15] = f2bf(p);
            }
        }

        // PV
        v8s pa0 = *(v8s*)&Pt[(w16 + l15) * PTP + quad * 8];
        v8s pa1 = *(v8s*)&Pt[(w16 + l15) * PTP + 32 + quad * 8];
        #pragma unroll
        for (int ht = 0; ht < 4; ++ht) {
            v8s bv0 = *(v8s*)&VtT[(ht * 16 + l15) * QP + quad * 8];
            v8s bv1 = *(v8s*)&VtT[(ht * 16 + l15) * QP + 32 + quad * 8];
            Oa[ht] = __builtin_amdgcn_mfma_f32_16x16x32_bf16(pa0, bv0, Oa[ht], 0, 0, 0);
            Oa[ht] = __builtin_amdgcn_mfma_f32_16x16x32_bf16(pa1, bv1, Oa[ht], 0, 0, 0);
        }
    }

    // ---- Epilogue: reduce row sums across quad, normalize, store ----
    #pragma unroll
    for (int v = 0; v < 4; ++v) {
        la[v] += __shfl_xor(la[v], 1);
        la[v] += __shfl_xor(la[v], 2);
        la[v] += __shfl_xor(la[v], 4);
        la[v] += __shfl_xor(la[v], 8);
        la[v] = 1.f / la[v];
    }
    #pragma unroll
    for (int ht = 0; ht < 4; ++ht) {
        #pragma unroll
        for (int v = 0; v < 4; ++v) {
            const int irow = w16 + quad * 4 + v;
            attn[(size_t)(b * Ss + i0 + irow) * NHh + n * 64 + ht * 16 + l15] =
                f2bf(Oa[ht][v] * la[v]);
        }
    }
}

// ---------------------------------------------------------------------------
// Fused residual-add + LayerNorm over E=1024; optional bf16 copy of output.
// ---------------------------------------------------------------------------
template<int W16>
__global__ __launch_bounds__(256) void add_ln_kernel(
    const float* __restrict__ a, const float* __restrict__ res,
    const float* __restrict__ g, const float* __restrict__ bet,
    float* __restrict__ out, us* __restrict__ out16)
{
    const int row = blockIdx.x;
    const int tid = threadIdx.x;
    const float* ar = a   + (size_t)row * Ee;
    const float* rr = res + (size_t)row * Ee;

    float vals[4];
    float lsum = 0.f, lsq = 0.f;
    #pragma unroll
    for (int it = 0; it < 4; ++it) {
        const int idx = tid + it * 256;
        const float vv = ar[idx] + rr[idx];
        vals[it] = vv;
        lsum += vv;
        lsq  = fmaf(vv, vv, lsq);
    }
    #pragma unroll
    for (int off = 32; off > 0; off >>= 1) {
        lsum += __shfl_down(lsum, off);
        lsq  += __shfl_down(lsq,  off);
    }
    __shared__ float w1[4], w2[4];
    if ((tid & 63) == 0) { w1[tid >> 6] = lsum; w2[tid >> 6] = lsq; }
    __syncthreads();
    const float sum  = w1[0] + w1[1] + w1[2] + w1[3];
    const float sq   = w2[0] + w2[1] + w2[2] + w2[3];
    const float mean = sum * (1.f / 1024.f);
    const float var  = sq * (1.f / 1024.f) - mean * mean;
    const float rstd = rsqrtf(var + 1e-12f);
    #pragma unroll
    for (int it = 0; it < 4; ++it) {
        const int idx = tid + it * 256;
        const float o = (vals[it] - mean) * rstd * g[idx] + bet[idx];
        out[(size_t)row * Ee + idx] = o;
        if (W16) out16[(size_t)row * Ee + idx] = f2bf(o);
    }
}

// ---------------------------------------------------------------------------
// Orchestration. Workspace layout (1 MB units), 90 MB total:
//   [ 0, 8)  x16      -> attn16 (ph3)  -> inner16 head (ph6)
//   [ 8,24)  rpe16    -> vT16 [8,16) (ph2.5), ao fp32 [16,24) (ph4)
//   [24,30)  Wqkv_t   [30,32) Wr_t   [32,34) Wo_t      (inner16 covers 0..32)
//   [34,42)  Wi_t     [42,50) Wout_t
//   [50,74)  qkv16    -> h16 [50,58) + hb fp32 [58,74) (ph5)
//   [74,90)  r16      -> out2 fp32 (ph7)
// ---------------------------------------------------------------------------
#define MB (1u << 20)

extern "C" void kernel_launch(void* const* d_in, const int* in_sizes, int n_in,
                              void* d_out, int out_size, void* d_ws, size_t ws_size,
                              hipStream_t stream)
{
    (void)in_sizes; (void)n_in; (void)out_size; (void)ws_size;

    const float* x    = (const float*)d_in[0];
    const float* cbf  = (const float*)d_in[1];
    const float* pbf  = (const float*)d_in[2];
    const float* rpe  = (const float*)d_in[3];
    const float* Wq   = (const float*)d_in[4];
    const float* Wk   = (const float*)d_in[5];
    const float* Wv   = (const float*)d_in[6];
    const float* Wr   = (const float*)d_in[7];
    const float* Wo   = (const float*)d_in[8];
    const float* ln1g = (const float*)d_in[9];
    const float* ln1b = (const float*)d_in[10];
    const float* Wi   = (const float*)d_in[11];
    const float* bi   = (const float*)d_in[12];
    const float* Wout = (const float*)d_in[13];
    const float* bout = (const float*)d_in[14];
    const float* ln2g = (const float*)d_in[15];
    const float* ln2b = (const float*)d_in[16];

    float* out = (float*)d_out;
    char*  ws  = (char*)d_ws;

    us* x16    = (us*)(ws + 0 * MB);
    us* rpe16  = (us*)(ws + 8 * MB);
    us* Wqkv_t = (us*)(ws + 24 * MB);           // [3072][1024]
    us* Wr_t   = (us*)(ws + 30 * MB);
    us* Wo_t   = (us*)(ws + 32 * MB);
    us* Wi_t   = (us*)(ws + 34 * MB);
    us* Wout_t = (us*)(ws + 42 * MB);
    us* qkv16  = (us*)(ws + 50 * MB);           // [BS][3072]
    us* r16    = (us*)(ws + 74 * MB);
    us* vT16   = (us*)(ws + 8 * MB);            // reuse rpe16 (after R gemm)
    us* attn16 = (us*)(ws + 0 * MB);            // reuse x16
    float* ao  = (float*)(ws + 16 * MB);        // [16,24)
    us* h16    = (us*)(ws + 50 * MB);           // reuse qkv16
    float* hb  = (float*)(ws + 58 * MB);        // reuse qkv16 tail
    us* inner16= (us*)(ws + 0 * MB);            // 0..32 MB
    float* out2= (float*)(ws + 74 * MB);        // reuse r16

    const dim3 blk(256);

    // Phase 1: converts + transposes (Wq/Wk/Wv concatenated into Wqkv_t)
    cvt_f32_bf16<<<dim3(4096), blk, 0, stream>>>(x,   x16);
    cvt_f32_bf16<<<dim3(8192), blk, 0, stream>>>(rpe, rpe16);
    tr_cvt<<<dim3(32, 32),  blk, 0, stream>>>(Wq,   Wqkv_t,                Ee,  NHh);
    tr_cvt<<<dim3(32, 32),  blk, 0, stream>>>(Wk,   Wqkv_t + 1024 * 1024,  Ee,  NHh);
    tr_cvt<<<dim3(32, 32),  blk, 0, stream>>>(Wv,   Wqkv_t + 2048 * 1024,  Ee,  NHh);
    tr_cvt<<<dim3(32, 32),  blk, 0, stream>>>(Wr,   Wr_t,   Ee,  NHh);
    tr_cvt<<<dim3(32, 32),  blk, 0, stream>>>(Wo,   Wo_t,   NHh, Ee);
    tr_cvt<<<dim3(128, 32), blk, 0, stream>>>(Wi,   Wi_t,   Ee,  Ff);
    tr_cvt<<<dim3(32, 128), blk, 0, stream>>>(Wout, Wout_t, Ff,  Ee);

    // Phase 2: fused QKV projection + R projection
    gemm_mfma<1,0,0><<<dim3(24, 32), blk, 0, stream>>>(x16,   Wqkv_t, nullptr, qkv16, BSs,   3072, Ee, QKVLD);
    gemm_mfma<1,0,0><<<dim3(8, 64),  blk, 0, stream>>>(rpe16, Wr_t,   nullptr, r16,   Bb*Rr, NHh,  Ee, NHh);

    // Phase 2.5: V transpose (v cols of qkv) -> [B,N,H,S]
    transpose_v<<<dim3(16, 64), blk, 0, stream>>>(qkv16 + 2048, vT16, QKVLD);

    // Phase 3: MFMA flash attention
    attn_mfma<<<dim3(16, Nn, Bb), blk, 0, stream>>>(qkv16, vT16, r16, cbf, pbf, attn16);

    // Phase 4: output projection (fp32 out)
    gemm_mfma<0,0,0><<<dim3(8, 32), blk, 0, stream>>>(attn16, Wo_t, nullptr, ao, BSs, Ee, NHh, Ee);

    // Phase 5: h = LN1(ao + x), fp32 + bf16
    add_ln_kernel<1><<<dim3(BSs), blk, 0, stream>>>(ao, x, ln1g, ln1b, hb, h16);

    // Phase 6: FFN1 (bias+relu, bf16 out)
    gemm_mfma<1,1,1><<<dim3(32, 32), blk, 0, stream>>>(h16, Wi_t, bi, inner16, BSs, Ff, Ee, Ff);

    // Phase 7: FFN2 (bias, fp32 out)
    gemm_mfma<0,1,0><<<dim3(8, 32), blk, 0, stream>>>(inner16, Wout_t, bout, out2, BSs, Ee, Ff, Ee);

    // Phase 8: out = LN2(out2 + h)
    add_ln_kernel<0><<<dim3(BSs), blk, 0, stream>>>(out2, hb, ln2g, ln2b, out, nullptr);
}

// Round 7
// 493.459 us; speedup vs baseline: 21.3487x; 1.0737x over previous
//
#include <hip/hip_runtime.h>
#include <math.h>

// Problem constants
#define Bb   4
#define Ss   1024
#define Ee   1024
#define Nn   16
#define Hh   64
#define Ff   4096
#define Rr   2048
#define NHh  1024   // N*H
#define BSs  4096   // B*S
#define QKVLD 3072  // fused qkv row stride

typedef short v8s __attribute__((ext_vector_type(8)));
typedef float v4f __attribute__((ext_vector_type(4)));
typedef unsigned int u32;
typedef unsigned short us;

static __device__ inline us f2bf(float f) {
    u32 u = __builtin_bit_cast(u32, f);
    u += 0x7fffu + ((u >> 16) & 1u);   // RNE
    return (us)(u >> 16);
}
static __device__ inline float bf2f(us h) {
    u32 u = ((u32)h) << 16;
    return __builtin_bit_cast(float, u);
}
static __device__ inline void g2lds16(const void* g, void* l) {
    __builtin_amdgcn_global_load_lds(
        (const __attribute__((address_space(1))) u32*)g,
        (__attribute__((address_space(3))) u32*)l, 16, 0, 0);
}

// ---------------------------------------------------------------------------
// fp32 -> bf16 elementwise for x (4096 blk) and rpe (8192 blk) in one launch.
// ---------------------------------------------------------------------------
__global__ __launch_bounds__(256) void cvt_x_rpe(
    const float* __restrict__ x, us* __restrict__ x16,
    const float* __restrict__ rpe, us* __restrict__ rpe16)
{
    const float* in; us* out; size_t base;
    if (blockIdx.x < 4096) { in = x; out = x16; base = (size_t)blockIdx.x; }
    else { in = rpe; out = rpe16; base = (size_t)(blockIdx.x - 4096); }
    const size_t i = (base * 256 + threadIdx.x) * 4;
    const float4 v = *reinterpret_cast<const float4*>(in + i);
    ushort4 o;
    o.x = f2bf(v.x); o.y = f2bf(v.y); o.z = f2bf(v.z); o.w = f2bf(v.w);
    *reinterpret_cast<ushort4*>(out + i) = o;
}

// ---------------------------------------------------------------------------
// Transpose + cvt body: in [K][N] fp32 -> out [N][K] bf16, 32x32 tile.
// ---------------------------------------------------------------------------
static __device__ __forceinline__ void tr_body(
    const float* __restrict__ in, us* __restrict__ out,
    int K, int N, int i0, int j0)
{
    __shared__ float t[32][33];
    const int r  = threadIdx.x >> 3;
    const int c4 = (threadIdx.x & 7) * 4;
    const float4 v = *reinterpret_cast<const float4*>(in + (size_t)(i0 + r) * N + j0 + c4);
    t[r][c4 + 0] = v.x; t[r][c4 + 1] = v.y; t[r][c4 + 2] = v.z; t[r][c4 + 3] = v.w;
    __syncthreads();
    ushort4 o;
    o.x = f2bf(t[c4 + 0][r]); o.y = f2bf(t[c4 + 1][r]);
    o.z = f2bf(t[c4 + 2][r]); o.w = f2bf(t[c4 + 3][r]);
    *reinterpret_cast<ushort4*>(out + (size_t)(j0 + r) * K + i0 + c4) = o;
}

// Five 1024x1024 weight transposes in one launch (z selects).
__global__ __launch_bounds__(256) void tr5(
    const float* __restrict__ w0, const float* __restrict__ w1,
    const float* __restrict__ w2, const float* __restrict__ w3,
    const float* __restrict__ w4,
    us* __restrict__ d0, us* __restrict__ d1, us* __restrict__ d2,
    us* __restrict__ d3, us* __restrict__ d4)
{
    const float* in; us* out;
    switch (blockIdx.z) {
        case 0: in = w0; out = d0; break;
        case 1: in = w1; out = d1; break;
        case 2: in = w2; out = d2; break;
        case 3: in = w3; out = d3; break;
        default: in = w4; out = d4; break;
    }
    tr_body(in, out, 1024, 1024, blockIdx.y * 32, blockIdx.x * 32);
}

// Wi [1024][4096] and Wout [4096][1024] in one launch.
__global__ __launch_bounds__(256) void tr_ffn(
    const float* __restrict__ wi, us* __restrict__ wi_t,
    const float* __restrict__ wo, us* __restrict__ wo_t)
{
    if (blockIdx.z == 0)
        tr_body(wi, wi_t, 1024, 4096, blockIdx.y * 32, blockIdx.x * 32);
    else
        tr_body(wo, wo_t, 4096, 1024, blockIdx.x * 32, blockIdx.y * 32);
}

// ---------------------------------------------------------------------------
// Per-(b,n) transpose of V: v16 (stride ld) [B,S,*] -> vT16 [B,N,H,S] bf16.
// ---------------------------------------------------------------------------
__global__ __launch_bounds__(256) void transpose_v(
    const us* __restrict__ v16, us* __restrict__ vT16, int ld)
{
    __shared__ us T[64][72];
    const int s0 = blockIdx.x * 64;
    const int bn = blockIdx.y;          // b*16 + n
    const int b  = bn >> 4, n = bn & 15;
    const int t  = threadIdx.x;
    {
        const int r = t >> 2, c = (t & 3) * 16;
        const uint4* src = (const uint4*)(v16 + (size_t)(b * Ss + s0 + r) * ld + n * 64 + c);
        *(uint4*)&T[r][c]     = src[0];
        *(uint4*)&T[r][c + 8] = src[1];
    }
    __syncthreads();
    {
        const int h = t >> 2, c2 = (t & 3) * 16;
        us tmp[16];
        #pragma unroll
        for (int u = 0; u < 16; ++u) tmp[u] = T[c2 + u][h];
        us* dst = vT16 + (size_t)(bn * 64 + h) * Ss + s0 + c2;
        *(uint4*)dst       = *(uint4*)tmp;
        *(uint4*)(dst + 8) = *(uint4*)(tmp + 8);
    }
}

// ---------------------------------------------------------------------------
// bf16 MFMA GEMM body: C = A[M,K] @ B^T (B as [N][K]).
// 128x128 tile, BK=64 (32 KB LDS), 4 waves 2x2, 4x4 of 16x16x32 each.
// XOR swizzle: LDS slot (r, sc) holds global chunk (r, sc ^ (r&7));
// fragment (row, cc) read at slot col cc ^ (row&7) -> balanced banks.
// 32 MFMA per barrier (2x the BK=32 amortization).
// ---------------------------------------------------------------------------
template<int OUT_BF16, int BIAS, int RELU>
static __device__ __forceinline__ void gemm_body(
    us* __restrict__ Asm, us* __restrict__ Bsm,
    const us* __restrict__ A, const us* __restrict__ B,
    const float* __restrict__ bias, void* __restrict__ Cv,
    int K, int ldC, int row0, int col0)
{
    const int tid  = threadIdx.x;
    const int lane = tid & 63;
    const int wave = tid >> 6;
    const int wr   = wave >> 1, wc = wave & 1;
    const int lrow = lane & 15;
    const int lq   = lane >> 4;
    const int h3   = lrow & 7;

    v4f acc[4][4];
    #pragma unroll
    for (int mt = 0; mt < 4; ++mt)
        #pragma unroll
        for (int nt = 0; nt < 4; ++nt)
            acc[mt][nt] = (v4f){0.f, 0.f, 0.f, 0.f};

    // staging source chunk cols (swizzled), one per u
    int srA[4], scC[4];
    #pragma unroll
    for (int u = 0; u < 4; ++u) {
        const int slot = u * 256 + tid;
        srA[u] = slot >> 3;
        scC[u] = ((slot & 7) ^ (srA[u] & 7)) * 8;
    }

    for (int k0 = 0; k0 < K; k0 += 64) {
        #pragma unroll
        for (int u = 0; u < 4; ++u) {
            const int slot = u * 256 + tid;
            g2lds16(A + (size_t)(row0 + srA[u]) * K + k0 + scC[u], &Asm[slot * 8]);
            g2lds16(B + (size_t)(col0 + srA[u]) * K + k0 + scC[u], &Bsm[slot * 8]);
        }
        __syncthreads();

        #pragma unroll
        for (int t = 0; t < 2; ++t) {
            const int cc = ((lq + 4 * t) ^ h3) * 8;
            v8s af[4], bf[4];
            #pragma unroll
            for (int mt = 0; mt < 4; ++mt)
                af[mt] = *reinterpret_cast<const v8s*>(&Asm[(wr * 64 + mt * 16 + lrow) * 64 + cc]);
            #pragma unroll
            for (int nt = 0; nt < 4; ++nt)
                bf[nt] = *reinterpret_cast<const v8s*>(&Bsm[(wc * 64 + nt * 16 + lrow) * 64 + cc]);
            #pragma unroll
            for (int mt = 0; mt < 4; ++mt)
                #pragma unroll
                for (int nt = 0; nt < 4; ++nt)
                    acc[mt][nt] = __builtin_amdgcn_mfma_f32_16x16x32_bf16(
                        af[mt], bf[nt], acc[mt][nt], 0, 0, 0);
        }
        __syncthreads();
    }

    #pragma unroll
    for (int nt = 0; nt < 4; ++nt) {
        const int col = col0 + wc * 64 + nt * 16 + lrow;
        const float bv = BIAS ? bias[col] : 0.f;
        #pragma unroll
        for (int mt = 0; mt < 4; ++mt) {
            #pragma unroll
            for (int v = 0; v < 4; ++v) {
                const int row = row0 + wr * 64 + mt * 16 + lq * 4 + v;
                float val = acc[mt][nt][v] + bv;
                if (RELU) val = fmaxf(val, 0.f);
                if (OUT_BF16)
                    ((us*)Cv)[(size_t)row * ldC + col] = f2bf(val);
                else
                    ((float*)Cv)[(size_t)row * ldC + col] = val;
            }
        }
    }
}

template<int OUT_BF16, int BIAS, int RELU>
__global__ __launch_bounds__(256) void gemm_mfma(
    const us* __restrict__ A, const us* __restrict__ B,
    const float* __restrict__ bias, void* __restrict__ Cv,
    int K, int ldC)
{
    __shared__ us Asm[128 * 64];
    __shared__ us Bsm[128 * 64];
    gemm_body<OUT_BF16, BIAS, RELU>(Asm, Bsm, A, B, bias, Cv, K, ldC,
                                    blockIdx.y * 128, blockIdx.x * 128);
}

// Fused QKV (768 blocks) + R (512 blocks) projection in one 1280-block launch.
__global__ __launch_bounds__(256) void gemm_qkv_r(
    const us* __restrict__ x16, const us* __restrict__ Wqkv,
    us* __restrict__ qkv, const us* __restrict__ rpe16,
    const us* __restrict__ Wr, us* __restrict__ rout)
{
    __shared__ us Asm[128 * 64];
    __shared__ us Bsm[128 * 64];
    const int bid = blockIdx.x;
    if (bid < 768) {
        gemm_body<1,0,0>(Asm, Bsm, x16, Wqkv, nullptr, qkv, Ee, QKVLD,
                         (bid / 24) * 128, (bid % 24) * 128);
    } else {
        const int b2 = bid - 768;
        gemm_body<1,0,0>(Asm, Bsm, rpe16, Wr, nullptr, rout, Ee, NHh,
                         (b2 / 8) * 128, (b2 % 8) * 128);
    }
}

// ---------------------------------------------------------------------------
// MFMA flash attention with rel-shift ring buffer (see R3-R5 notes).
// ---------------------------------------------------------------------------
#define QP 72      // pitch for qc/qp/Kt/Rt/VtT
#define PTP 68     // Pt pitch
#define RINGP 130  // ring pitch

__global__ __launch_bounds__(256) void attn_mfma(
    const us* __restrict__ qkv, const us* __restrict__ vT16,
    const us* __restrict__ r16,
    const float* __restrict__ cb, const float* __restrict__ pb,
    us* __restrict__ attn)
{
    __shared__ __align__(16) char smem[52992];
    us* qcS  = (us*)smem;              // prologue only
    us* qpS  = (us*)(smem + 9216);     // prologue only
    us* Kt   = (us*)smem;              // main loop (overlays qcS)
    us* Rt   = (us*)(smem + 9216);     // main loop (overlays qpS)
    us* VtT  = (us*)(smem + 18432);
    us* ring = (us*)(smem + 27648);    // 64 x 130 bf16
    us* Pt   = (us*)(smem + 44288);    // 64 x 68 bf16

    const int i0 = blockIdx.x * 64;
    const int n  = blockIdx.y;
    const int b  = blockIdx.z;
    const int tid  = threadIdx.x;
    const int lane = tid & 63;
    const int w    = tid >> 6;
    const int quad = lane >> 4;
    const int l15  = lane & 15;
    const int w16  = w * 16;

    // ---- Prologue: stage qc = (q+cb)*0.125, qp = (q+pb)*0.125 (bf16) ----
    {
        const int r = tid >> 2, c = (tid & 3) * 16;
        const uint4* src = (const uint4*)(qkv + (size_t)(b * Ss + i0 + r) * QKVLD + n * 64 + c);
        uint4 qa = src[0], qb = src[1];
        us qs[16];
        *(uint4*)qs       = qa;
        *(uint4*)(qs + 8) = qb;
        const float* cbp = cb + n * 64 + c;
        const float* pbp = pb + n * 64 + c;
        us oc[16], op[16];
        #pragma unroll
        for (int u = 0; u < 16; ++u) {
            const float qf = bf2f(qs[u]);
            oc[u] = f2bf((qf + cbp[u]) * 0.125f);
            op[u] = f2bf((qf + pbp[u]) * 0.125f);
        }
        *(uint4*)&qcS[r * QP + c]     = *(uint4*)oc;
        *(uint4*)&qcS[r * QP + c + 8] = *(uint4*)(oc + 8);
        *(uint4*)&qpS[r * QP + c]     = *(uint4*)op;
        *(uint4*)&qpS[r * QP + c + 8] = *(uint4*)(op + 8);
    }
    __syncthreads();

    // A-fragments in registers (wave w owns queries [w16, w16+16))
    v8s aqc0 = *(v8s*)&qcS[(w16 + l15) * QP + quad * 8];
    v8s aqc1 = *(v8s*)&qcS[(w16 + l15) * QP + 32 + quad * 8];
    v8s aqp0 = *(v8s*)&qpS[(w16 + l15) * QP + quad * 8];
    v8s aqp1 = *(v8s*)&qpS[(w16 + l15) * QP + 32 + quad * 8];
    __syncthreads();   // all reads done before Kt/Rt overlay

    const int c0 = Ss - i0;   // l at j-i diag base

    // ---- Bootstrap: pos chunk l in [c0-64, c0) ----
    {
        const int lbase = c0 - 64;
        const int r = tid >> 2, c = (tid & 3) * 16;
        const uint4* src = (const uint4*)(r16 + (size_t)(b * Rr + lbase + r) * NHh + n * 64 + c);
        *(uint4*)&Rt[r * QP + c]     = src[0];
        *(uint4*)&Rt[r * QP + c + 8] = src[1];
        __syncthreads();
        const v4f z = (v4f){0.f, 0.f, 0.f, 0.f};
        #pragma unroll
        for (int t = 0; t < 4; ++t) {
            v8s br0 = *(v8s*)&Rt[(t * 16 + l15) * QP + quad * 8];
            v8s br1 = *(v8s*)&Rt[(t * 16 + l15) * QP + 32 + quad * 8];
            v4f pp = __builtin_amdgcn_mfma_f32_16x16x32_bf16(aqp0, br0, z, 0, 0, 0);
            pp = __builtin_amdgcn_mfma_f32_16x16x32_bf16(aqp1, br1, pp, 0, 0, 0);
            #pragma unroll
            for (int v = 0; v < 4; ++v)
                ring[(w16 + quad * 4 + v) * RINGP + ((lbase + t * 16 + l15) & 127)] = f2bf(pp[v]);
        }
    }

    v4f Oa[4];
    #pragma unroll
    for (int t = 0; t < 4; ++t) Oa[t] = (v4f){0.f, 0.f, 0.f, 0.f};
    float la[4] = {0.f, 0.f, 0.f, 0.f};

    // ---- Main flash loop over key tiles ----
    for (int j0 = 0; j0 < Ss; j0 += 64) {
        __syncthreads();   // prev iter LDS reads done
        {
            const int r = tid >> 2, c = (tid & 3) * 16;
            const int lbase = j0 + c0;
            const uint4* sk = (const uint4*)(qkv + (size_t)(b * Ss + j0 + r) * QKVLD + NHh + n * 64 + c);
            const uint4* sr = (const uint4*)(r16 + (size_t)(b * Rr + lbase + r) * NHh + n * 64 + c);
            const uint4* sv = (const uint4*)(vT16 + (size_t)((b * 16 + n) * 64 + r) * Ss + j0 + c);
            uint4 k0v = sk[0], k1v = sk[1];
            uint4 r0v = sr[0], r1v = sr[1];
            uint4 v0v = sv[0], v1v = sv[1];
            *(uint4*)&Kt[r * QP + c]      = k0v;
            *(uint4*)&Kt[r * QP + c + 8]  = k1v;
            *(uint4*)&Rt[r * QP + c]      = r0v;
            *(uint4*)&Rt[r * QP + c + 8]  = r1v;
            *(uint4*)&VtT[r * QP + c]     = v0v;
            *(uint4*)&VtT[r * QP + c + 8] = v1v;
        }
        __syncthreads();

        const v4f z = (v4f){0.f, 0.f, 0.f, 0.f};
        // Content scores + pos chunk
        v4f sc[4];
        #pragma unroll
        for (int t = 0; t < 4; ++t) {
            v8s bk0 = *(v8s*)&Kt[(t * 16 + l15) * QP + quad * 8];
            v8s bk1 = *(v8s*)&Kt[(t * 16 + l15) * QP + 32 + quad * 8];
            sc[t] = __builtin_amdgcn_mfma_f32_16x16x32_bf16(aqc0, bk0, z, 0, 0, 0);
            sc[t] = __builtin_amdgcn_mfma_f32_16x16x32_bf16(aqc1, bk1, sc[t], 0, 0, 0);
        }
        const int lbase = j0 + c0;
        #pragma unroll
        for (int t = 0; t < 4; ++t) {
            v8s br0 = *(v8s*)&Rt[(t * 16 + l15) * QP + quad * 8];
            v8s br1 = *(v8s*)&Rt[(t * 16 + l15) * QP + 32 + quad * 8];
            v4f pp = __builtin_amdgcn_mfma_f32_16x16x32_bf16(aqp0, br0, z, 0, 0, 0);
            pp = __builtin_amdgcn_mfma_f32_16x16x32_bf16(aqp1, br1, pp, 0, 0, 0);
            #pragma unroll
            for (int v = 0; v < 4; ++v)
                ring[(w16 + quad * 4 + v) * RINGP + ((lbase + t * 16 + l15) & 127)] = f2bf(pp[v]);
        }

        // Scores -> exp -> Pt (wave-private rows; same-wave LDS dep in-order)
        #pragma unroll
        for (int t = 0; t < 4; ++t) {
            #pragma unroll
            for (int v = 0; v < 4; ++v) {
                const int irow = w16 + quad * 4 + v;
                const int l = (j0 + t * 16 + l15) + Ss - (i0 + irow);
                const float pos = bf2f(ring[irow * RINGP + (l & 127)]);
                const float p = __expf(sc[t][v] + pos);
                la[v] += p;
                Pt[irow * PTP + t * 16 + l15] = f2bf(p);
            }
        }

        // PV
        v8s pa0 = *(v8s*)&Pt[(w16 + l15) * PTP + quad * 8];
        v8s pa1 = *(v8s*)&Pt[(w16 + l15) * PTP + 32 + quad * 8];
        #pragma unroll
        for (int ht = 0; ht < 4; ++ht) {
            v8s bv0 = *(v8s*)&VtT[(ht * 16 + l15) * QP + quad * 8];
            v8s bv1 = *(v8s*)&VtT[(ht * 16 + l15) * QP + 32 + quad * 8];
            Oa[ht] = __builtin_amdgcn_mfma_f32_16x16x32_bf16(pa0, bv0, Oa[ht], 0, 0, 0);
            Oa[ht] = __builtin_amdgcn_mfma_f32_16x16x32_bf16(pa1, bv1, Oa[ht], 0, 0, 0);
        }
    }

    // ---- Epilogue: reduce row sums across quad, normalize, store ----
    #pragma unroll
    for (int v = 0; v < 4; ++v) {
        la[v] += __shfl_xor(la[v], 1);
        la[v] += __shfl_xor(la[v], 2);
        la[v] += __shfl_xor(la[v], 4);
        la[v] += __shfl_xor(la[v], 8);
        la[v] = 1.f / la[v];
    }
    #pragma unroll
    for (int ht = 0; ht < 4; ++ht) {
        #pragma unroll
        for (int v = 0; v < 4; ++v) {
            const int irow = w16 + quad * 4 + v;
            attn[(size_t)(b * Ss + i0 + irow) * NHh + n * 64 + ht * 16 + l15] =
                f2bf(Oa[ht][v] * la[v]);
        }
    }
}

// ---------------------------------------------------------------------------
// Fused residual-add + LayerNorm over E=1024; optional bf16 copy of output.
// ---------------------------------------------------------------------------
template<int W16>
__global__ __launch_bounds__(256) void add_ln_kernel(
    const float* __restrict__ a, const float* __restrict__ res,
    const float* __restrict__ g, const float* __restrict__ bet,
    float* __restrict__ out, us* __restrict__ out16)
{
    const int row = blockIdx.x;
    const int tid = threadIdx.x;
    const float* ar = a   + (size_t)row * Ee;
    const float* rr = res + (size_t)row * Ee;

    float vals[4];
    float lsum = 0.f, lsq = 0.f;
    #pragma unroll
    for (int it = 0; it < 4; ++it) {
        const int idx = tid + it * 256;
        const float vv = ar[idx] + rr[idx];
        vals[it] = vv;
        lsum += vv;
        lsq  = fmaf(vv, vv, lsq);
    }
    #pragma unroll
    for (int off = 32; off > 0; off >>= 1) {
        lsum += __shfl_down(lsum, off);
        lsq  += __shfl_down(lsq,  off);
    }
    __shared__ float w1[4], w2[4];
    if ((tid & 63) == 0) { w1[tid >> 6] = lsum; w2[tid >> 6] = lsq; }
    __syncthreads();
    const float sum  = w1[0] + w1[1] + w1[2] + w1[3];
    const float sq   = w2[0] + w2[1] + w2[2] + w2[3];
    const float mean = sum * (1.f / 1024.f);
    const float var  = sq * (1.f / 1024.f) - mean * mean;
    const float rstd = rsqrtf(var + 1e-12f);
    #pragma unroll
    for (int it = 0; it < 4; ++it) {
        const int idx = tid + it * 256;
        const float o = (vals[it] - mean) * rstd * g[idx] + bet[idx];
        out[(size_t)row * Ee + idx] = o;
        if (W16) out16[(size_t)row * Ee + idx] = f2bf(o);
    }
}

// ---------------------------------------------------------------------------
// Orchestration. Workspace layout (1 MB units), 90 MB total:
//   [ 0, 8)  x16      -> attn16 (ph3)  -> inner16 head (ph6)
//   [ 8,24)  rpe16    -> vT16 [8,16) (ph2.5), ao fp32 [16,24) (ph4)
//   [24,30)  Wqkv_t   [30,32) Wr_t   [32,34) Wo_t      (inner16 covers 0..32)
//   [34,42)  Wi_t     [42,50) Wout_t
//   [50,74)  qkv16    -> h16 [50,58) + hb fp32 [58,74) (ph5)
//   [74,90)  r16      -> out2 fp32 (ph7)
// ---------------------------------------------------------------------------
#define MB (1u << 20)

extern "C" void kernel_launch(void* const* d_in, const int* in_sizes, int n_in,
                              void* d_out, int out_size, void* d_ws, size_t ws_size,
                              hipStream_t stream)
{
    (void)in_sizes; (void)n_in; (void)out_size; (void)ws_size;

    const float* x    = (const float*)d_in[0];
    const float* cbf  = (const float*)d_in[1];
    const float* pbf  = (const float*)d_in[2];
    const float* rpe  = (const float*)d_in[3];
    const float* Wq   = (const float*)d_in[4];
    const float* Wk   = (const float*)d_in[5];
    const float* Wv   = (const float*)d_in[6];
    const float* Wr   = (const float*)d_in[7];
    const float* Wo   = (const float*)d_in[8];
    const float* ln1g = (const float*)d_in[9];
    const float* ln1b = (const float*)d_in[10];
    const float* Wi   = (const float*)d_in[11];
    const float* bi   = (const float*)d_in[12];
    const float* Wout = (const float*)d_in[13];
    const float* bout = (const float*)d_in[14];
    const float* ln2g = (const float*)d_in[15];
    const float* ln2b = (const float*)d_in[16];

    float* out = (float*)d_out;
    char*  ws  = (char*)d_ws;

    us* x16    = (us*)(ws + 0 * MB);
    us* rpe16  = (us*)(ws + 8 * MB);
    us* Wqkv_t = (us*)(ws + 24 * MB);           // [3072][1024]
    us* Wr_t   = (us*)(ws + 30 * MB);
    us* Wo_t   = (us*)(ws + 32 * MB);
    us* Wi_t   = (us*)(ws + 34 * MB);
    us* Wout_t = (us*)(ws + 42 * MB);
    us* qkv16  = (us*)(ws + 50 * MB);           // [BS][3072]
    us* r16    = (us*)(ws + 74 * MB);
    us* vT16   = (us*)(ws + 8 * MB);            // reuse rpe16 (after qkv_r gemm)
    us* attn16 = (us*)(ws + 0 * MB);            // reuse x16
    float* ao  = (float*)(ws + 16 * MB);        // [16,24)
    us* h16    = (us*)(ws + 50 * MB);           // reuse qkv16
    float* hb  = (float*)(ws + 58 * MB);        // reuse qkv16 tail
    us* inner16= (us*)(ws + 0 * MB);            // 0..32 MB
    float* out2= (float*)(ws + 74 * MB);        // reuse r16

    const dim3 blk(256);

    // Phase 1: converts + transposes (merged launches)
    cvt_x_rpe<<<dim3(12288), blk, 0, stream>>>(x, x16, rpe, rpe16);
    tr5<<<dim3(32, 32, 5), blk, 0, stream>>>(
        Wq, Wk, Wv, Wr, Wo,
        Wqkv_t, Wqkv_t + 1024 * 1024, Wqkv_t + 2048 * 1024, Wr_t, Wo_t);
    tr_ffn<<<dim3(128, 32, 2), blk, 0, stream>>>(Wi, Wi_t, Wout, Wout_t);

    // Phase 2: fused QKV + R projection (one 1280-block dispatch)
    gemm_qkv_r<<<dim3(1280), blk, 0, stream>>>(x16, Wqkv_t, qkv16, rpe16, Wr_t, r16);

    // Phase 2.5: V transpose (v cols of qkv) -> [B,N,H,S]
    transpose_v<<<dim3(16, 64), blk, 0, stream>>>(qkv16 + 2048, vT16, QKVLD);

    // Phase 3: MFMA flash attention
    attn_mfma<<<dim3(16, Nn, Bb), blk, 0, stream>>>(qkv16, vT16, r16, cbf, pbf, attn16);

    // Phase 4: output projection (fp32 out)
    gemm_mfma<0,0,0><<<dim3(8, 32), blk, 0, stream>>>(attn16, Wo_t, nullptr, ao, NHh, Ee);

    // Phase 5: h = LN1(ao + x), fp32 + bf16
    add_ln_kernel<1><<<dim3(BSs), blk, 0, stream>>>(ao, x, ln1g, ln1b, hb, h16);

    // Phase 6: FFN1 (bias+relu, bf16 out)
    gemm_mfma<1,1,1><<<dim3(32, 32), blk, 0, stream>>>(h16, Wi_t, bi, inner16, Ee, Ff);

    // Phase 7: FFN2 (bias, fp32 out)
    gemm_mfma<0,1,0><<<dim3(8, 32), blk, 0, stream>>>(inner16, Wout_t, bout, out2, Ff, Ee);

    // Phase 8: out = LN2(out2 + h)
    add_ln_kernel<0><<<dim3(BSs), blk, 0, stream>>>(out2, hb, ln2g, ln2b, out, nullptr);
}

// Round 8
// 461.422 us; speedup vs baseline: 22.8310x; 1.0694x over previous
//
#include <hip/hip_runtime.h>
#include <math.h>

// Problem constants
#define Bb   4
#define Ss   1024
#define Ee   1024
#define Nn   16
#define Hh   64
#define Ff   4096
#define Rr   2048
#define NHh  1024   // N*H
#define BSs  4096   // B*S
#define QKVLD 3072  // fused qkv row stride

typedef short v8s __attribute__((ext_vector_type(8)));
typedef float v4f __attribute__((ext_vector_type(4)));
typedef unsigned int u32;
typedef unsigned short us;

static __device__ inline us f2bf(float f) {
    u32 u = __builtin_bit_cast(u32, f);
    u += 0x7fffu + ((u >> 16) & 1u);   // RNE
    return (us)(u >> 16);
}
static __device__ inline float bf2f(us h) {
    u32 u = ((u32)h) << 16;
    return __builtin_bit_cast(float, u);
}
static __device__ inline void g2lds16(const void* g, void* l) {
    __builtin_amdgcn_global_load_lds(
        (const __attribute__((address_space(1))) u32*)g,
        (__attribute__((address_space(3))) u32*)l, 16, 0, 0);
}

// ---------------------------------------------------------------------------
// fp32 -> bf16 elementwise for x (4096 blk) and rpe (8192 blk) in one launch.
// ---------------------------------------------------------------------------
__global__ __launch_bounds__(256) void cvt_x_rpe(
    const float* __restrict__ x, us* __restrict__ x16,
    const float* __restrict__ rpe, us* __restrict__ rpe16)
{
    const float* in; us* out; size_t base;
    if (blockIdx.x < 4096) { in = x; out = x16; base = (size_t)blockIdx.x; }
    else { in = rpe; out = rpe16; base = (size_t)(blockIdx.x - 4096); }
    const size_t i = (base * 256 + threadIdx.x) * 4;
    const float4 v = *reinterpret_cast<const float4*>(in + i);
    ushort4 o;
    o.x = f2bf(v.x); o.y = f2bf(v.y); o.z = f2bf(v.z); o.w = f2bf(v.w);
    *reinterpret_cast<ushort4*>(out + i) = o;
}

// ---------------------------------------------------------------------------
// Transpose + cvt body: in [K][N] fp32 -> out [N][K] bf16, 32x32 tile.
// ---------------------------------------------------------------------------
static __device__ __forceinline__ void tr_body(
    const float* __restrict__ in, us* __restrict__ out,
    int K, int N, int i0, int j0)
{
    __shared__ float t[32][33];
    const int r  = threadIdx.x >> 3;
    const int c4 = (threadIdx.x & 7) * 4;
    const float4 v = *reinterpret_cast<const float4*>(in + (size_t)(i0 + r) * N + j0 + c4);
    t[r][c4 + 0] = v.x; t[r][c4 + 1] = v.y; t[r][c4 + 2] = v.z; t[r][c4 + 3] = v.w;
    __syncthreads();
    ushort4 o;
    o.x = f2bf(t[c4 + 0][r]); o.y = f2bf(t[c4 + 1][r]);
    o.z = f2bf(t[c4 + 2][r]); o.w = f2bf(t[c4 + 3][r]);
    *reinterpret_cast<ushort4*>(out + (size_t)(j0 + r) * K + i0 + c4) = o;
}

// Five 1024x1024 weight transposes in one launch (z selects).
__global__ __launch_bounds__(256) void tr5(
    const float* __restrict__ w0, const float* __restrict__ w1,
    const float* __restrict__ w2, const float* __restrict__ w3,
    const float* __restrict__ w4,
    us* __restrict__ d0, us* __restrict__ d1, us* __restrict__ d2,
    us* __restrict__ d3, us* __restrict__ d4)
{
    const float* in; us* out;
    switch (blockIdx.z) {
        case 0: in = w0; out = d0; break;
        case 1: in = w1; out = d1; break;
        case 2: in = w2; out = d2; break;
        case 3: in = w3; out = d3; break;
        default: in = w4; out = d4; break;
    }
    tr_body(in, out, 1024, 1024, blockIdx.y * 32, blockIdx.x * 32);
}

// Wi [1024][4096] and Wout [4096][1024] in one launch.
__global__ __launch_bounds__(256) void tr_ffn(
    const float* __restrict__ wi, us* __restrict__ wi_t,
    const float* __restrict__ wo, us* __restrict__ wo_t)
{
    if (blockIdx.z == 0)
        tr_body(wi, wi_t, 1024, 4096, blockIdx.y * 32, blockIdx.x * 32);
    else
        tr_body(wo, wo_t, 4096, 1024, blockIdx.x * 32, blockIdx.y * 32);
}

// ---------------------------------------------------------------------------
// Per-(b,n) transpose of V: v16 (stride ld) [B,S,*] -> vT16 [B,N,H,S] bf16.
// ---------------------------------------------------------------------------
__global__ __launch_bounds__(256) void transpose_v(
    const us* __restrict__ v16, us* __restrict__ vT16, int ld)
{
    __shared__ us T[64][72];
    const int s0 = blockIdx.x * 64;
    const int bn = blockIdx.y;          // b*16 + n
    const int b  = bn >> 4, n = bn & 15;
    const int t  = threadIdx.x;
    {
        const int r = t >> 2, c = (t & 3) * 16;
        const uint4* src = (const uint4*)(v16 + (size_t)(b * Ss + s0 + r) * ld + n * 64 + c);
        *(uint4*)&T[r][c]     = src[0];
        *(uint4*)&T[r][c + 8] = src[1];
    }
    __syncthreads();
    {
        const int h = t >> 2, c2 = (t & 3) * 16;
        us tmp[16];
        #pragma unroll
        for (int u = 0; u < 16; ++u) tmp[u] = T[c2 + u][h];
        us* dst = vT16 + (size_t)(bn * 64 + h) * Ss + s0 + c2;
        *(uint4*)dst       = *(uint4*)tmp;
        *(uint4*)(dst + 8) = *(uint4*)(tmp + 8);
    }
}

// ---------------------------------------------------------------------------
// bf16 MFMA GEMM body: C = A[M,K] @ B^T (B as [N][K]).
// Tile: (MT*32) x 128, BK=64, 4 waves 2x2; wave does MTx4 of 16x16x32.
// XOR swizzle: LDS slot (r, sc) holds global chunk (r, sc ^ (r&7));
// fragment (row, cc) read at slot col cc ^ (row&7) -> balanced banks.
// MT=4: 128-row tile (32 MFMA/barrier). MT=2: 64-row tile -> 2x grid for
// co-residency on grids that would otherwise be 1 block/CU.
// ---------------------------------------------------------------------------
template<int MT, int OUT_BF16, int BIAS, int RELU>
static __device__ __forceinline__ void gemm_body(
    us* __restrict__ Asm, us* __restrict__ Bsm,
    const us* __restrict__ A, const us* __restrict__ B,
    const float* __restrict__ bias, void* __restrict__ Cv,
    int K, int ldC, int row0, int col0)
{
    const int tid  = threadIdx.x;
    const int lane = tid & 63;
    const int wave = tid >> 6;
    const int wr   = wave >> 1, wc = wave & 1;
    const int lrow = lane & 15;
    const int lq   = lane >> 4;
    const int h3   = lrow & 7;

    v4f acc[MT][4];
    #pragma unroll
    for (int mt = 0; mt < MT; ++mt)
        #pragma unroll
        for (int nt = 0; nt < 4; ++nt)
            acc[mt][nt] = (v4f){0.f, 0.f, 0.f, 0.f};

    for (int k0 = 0; k0 < K; k0 += 64) {
        #pragma unroll
        for (int u = 0; u < MT; ++u) {
            const int slot = u * 256 + tid;
            const int sr = slot >> 3;
            const int sc = ((slot & 7) ^ (sr & 7)) * 8;
            g2lds16(A + (size_t)(row0 + sr) * K + k0 + sc, &Asm[slot * 8]);
        }
        #pragma unroll
        for (int u = 0; u < 4; ++u) {
            const int slot = u * 256 + tid;
            const int sr = slot >> 3;
            const int sc = ((slot & 7) ^ (sr & 7)) * 8;
            g2lds16(B + (size_t)(col0 + sr) * K + k0 + sc, &Bsm[slot * 8]);
        }
        __syncthreads();

        #pragma unroll
        for (int t = 0; t < 2; ++t) {
            const int cc = ((lq + 4 * t) ^ h3) * 8;
            v8s af[MT], bf[4];
            #pragma unroll
            for (int mt = 0; mt < MT; ++mt)
                af[mt] = *reinterpret_cast<const v8s*>(
                    &Asm[(wr * (MT * 16) + mt * 16 + lrow) * 64 + cc]);
            #pragma unroll
            for (int nt = 0; nt < 4; ++nt)
                bf[nt] = *reinterpret_cast<const v8s*>(
                    &Bsm[(wc * 64 + nt * 16 + lrow) * 64 + cc]);
            #pragma unroll
            for (int mt = 0; mt < MT; ++mt)
                #pragma unroll
                for (int nt = 0; nt < 4; ++nt)
                    acc[mt][nt] = __builtin_amdgcn_mfma_f32_16x16x32_bf16(
                        af[mt], bf[nt], acc[mt][nt], 0, 0, 0);
        }
        __syncthreads();
    }

    #pragma unroll
    for (int nt = 0; nt < 4; ++nt) {
        const int col = col0 + wc * 64 + nt * 16 + lrow;
        const float bv = BIAS ? bias[col] : 0.f;
        #pragma unroll
        for (int mt = 0; mt < MT; ++mt) {
            #pragma unroll
            for (int v = 0; v < 4; ++v) {
                const int row = row0 + wr * (MT * 16) + mt * 16 + lq * 4 + v;
                float val = acc[mt][nt][v] + bv;
                if (RELU) val = fmaxf(val, 0.f);
                if (OUT_BF16)
                    ((us*)Cv)[(size_t)row * ldC + col] = f2bf(val);
                else
                    ((float*)Cv)[(size_t)row * ldC + col] = val;
            }
        }
    }
}

template<int MT, int OUT_BF16, int BIAS, int RELU>
__global__ __launch_bounds__(256) void gemm_tile(
    const us* __restrict__ A, const us* __restrict__ B,
    const float* __restrict__ bias, void* __restrict__ Cv,
    int K, int ldC)
{
    __shared__ us Asm[MT * 32 * 64];
    __shared__ us Bsm[128 * 64];
    gemm_body<MT, OUT_BF16, BIAS, RELU>(Asm, Bsm, A, B, bias, Cv, K, ldC,
                                        blockIdx.y * (MT * 32), blockIdx.x * 128);
}

// Fused QKV (768 blocks) + R (512 blocks) projection in one 1280-block launch.
__global__ __launch_bounds__(256) void gemm_qkv_r(
    const us* __restrict__ x16, const us* __restrict__ Wqkv,
    us* __restrict__ qkv, const us* __restrict__ rpe16,
    const us* __restrict__ Wr, us* __restrict__ rout)
{
    __shared__ us Asm[128 * 64];
    __shared__ us Bsm[128 * 64];
    const int bid = blockIdx.x;
    if (bid < 768) {
        gemm_body<4,1,0,0>(Asm, Bsm, x16, Wqkv, nullptr, qkv, Ee, QKVLD,
                           (bid / 24) * 128, (bid % 24) * 128);
    } else {
        const int b2 = bid - 768;
        gemm_body<4,1,0,0>(Asm, Bsm, rpe16, Wr, nullptr, rout, Ee, NHh,
                           (b2 / 8) * 128, (b2 % 8) * 128);
    }
}

// ---------------------------------------------------------------------------
// MFMA flash attention with rel-shift ring buffer (see R3-R6 notes).
// Bank-tuned pitches: RINGP=132 (quad stride 8 banks: writes perfect, reads
// <=2-way), PTP=68 (quad stride 8: writes perfect). All b128 ops balanced.
// ---------------------------------------------------------------------------
#define QP 72      // pitch for qc/qp/Kt/Rt/VtT
#define PTP 68     // Pt pitch
#define RINGP 132  // ring pitch

__global__ __launch_bounds__(256) void attn_mfma(
    const us* __restrict__ qkv, const us* __restrict__ vT16,
    const us* __restrict__ r16,
    const float* __restrict__ cb, const float* __restrict__ pb,
    us* __restrict__ attn)
{
    __shared__ __align__(16) char smem[53248];
    us* qcS  = (us*)smem;              // prologue only
    us* qpS  = (us*)(smem + 9216);     // prologue only
    us* Kt   = (us*)smem;              // main loop (overlays qcS)
    us* Rt   = (us*)(smem + 9216);     // main loop (overlays qpS)
    us* VtT  = (us*)(smem + 18432);
    us* ring = (us*)(smem + 27648);    // 64 x 132 bf16 = 16896 B
    us* Pt   = (us*)(smem + 44544);    // 64 x 68 bf16 = 8704 B

    const int i0 = blockIdx.x * 64;
    const int n  = blockIdx.y;
    const int b  = blockIdx.z;
    const int tid  = threadIdx.x;
    const int lane = tid & 63;
    const int w    = tid >> 6;
    const int quad = lane >> 4;
    const int l15  = lane & 15;
    const int w16  = w * 16;

    // ---- Prologue: stage qc = (q+cb)*0.125, qp = (q+pb)*0.125 (bf16) ----
    {
        const int r = tid >> 2, c = (tid & 3) * 16;
        const uint4* src = (const uint4*)(qkv + (size_t)(b * Ss + i0 + r) * QKVLD + n * 64 + c);
        uint4 qa = src[0], qb = src[1];
        us qs[16];
        *(uint4*)qs       = qa;
        *(uint4*)(qs + 8) = qb;
        const float* cbp = cb + n * 64 + c;
        const float* pbp = pb + n * 64 + c;
        us oc[16], op[16];
        #pragma unroll
        for (int u = 0; u < 16; ++u) {
            const float qf = bf2f(qs[u]);
            oc[u] = f2bf((qf + cbp[u]) * 0.125f);
            op[u] = f2bf((qf + pbp[u]) * 0.125f);
        }
        *(uint4*)&qcS[r * QP + c]     = *(uint4*)oc;
        *(uint4*)&qcS[r * QP + c + 8] = *(uint4*)(oc + 8);
        *(uint4*)&qpS[r * QP + c]     = *(uint4*)op;
        *(uint4*)&qpS[r * QP + c + 8] = *(uint4*)(op + 8);
    }
    __syncthreads();

    // A-fragments in registers (wave w owns queries [w16, w16+16))
    v8s aqc0 = *(v8s*)&qcS[(w16 + l15) * QP + quad * 8];
    v8s aqc1 = *(v8s*)&qcS[(w16 + l15) * QP + 32 + quad * 8];
    v8s aqp0 = *(v8s*)&qpS[(w16 + l15) * QP + quad * 8];
    v8s aqp1 = *(v8s*)&qpS[(w16 + l15) * QP + 32 + quad * 8];
    __syncthreads();   // all reads done before Kt/Rt overlay

    const int c0 = Ss - i0;   // l at j-i diag base

    // ---- Bootstrap: pos chunk l in [c0-64, c0) ----
    {
        const int lbase = c0 - 64;
        const int r = tid >> 2, c = (tid & 3) * 16;
        const uint4* src = (const uint4*)(r16 + (size_t)(b * Rr + lbase + r) * NHh + n * 64 + c);
        *(uint4*)&Rt[r * QP + c]     = src[0];
        *(uint4*)&Rt[r * QP + c + 8] = src[1];
        __syncthreads();
        const v4f z = (v4f){0.f, 0.f, 0.f, 0.f};
        #pragma unroll
        for (int t = 0; t < 4; ++t) {
            v8s br0 = *(v8s*)&Rt[(t * 16 + l15) * QP + quad * 8];
            v8s br1 = *(v8s*)&Rt[(t * 16 + l15) * QP + 32 + quad * 8];
            v4f pp = __builtin_amdgcn_mfma_f32_16x16x32_bf16(aqp0, br0, z, 0, 0, 0);
            pp = __builtin_amdgcn_mfma_f32_16x16x32_bf16(aqp1, br1, pp, 0, 0, 0);
            #pragma unroll
            for (int v = 0; v < 4; ++v)
                ring[(w16 + quad * 4 + v) * RINGP + ((lbase + t * 16 + l15) & 127)] = f2bf(pp[v]);
        }
    }

    v4f Oa[4];
    #pragma unroll
    for (int t = 0; t < 4; ++t) Oa[t] = (v4f){0.f, 0.f, 0.f, 0.f};
    float la[4] = {0.f, 0.f, 0.f, 0.f};

    // ---- Main flash loop over key tiles ----
    for (int j0 = 0; j0 < Ss; j0 += 64) {
        __syncthreads();   // prev iter LDS reads done
        {
            const int r = tid >> 2, c = (tid & 3) * 16;
            const int lbase = j0 + c0;
            const uint4* sk = (const uint4*)(qkv + (size_t)(b * Ss + j0 + r) * QKVLD + NHh + n * 64 + c);
            const uint4* sr = (const uint4*)(r16 + (size_t)(b * Rr + lbase + r) * NHh + n * 64 + c);
            const uint4* sv = (const uint4*)(vT16 + (size_t)((b * 16 + n) * 64 + r) * Ss + j0 + c);
            uint4 k0v = sk[0], k1v = sk[1];
            uint4 r0v = sr[0], r1v = sr[1];
            uint4 v0v = sv[0], v1v = sv[1];
            *(uint4*)&Kt[r * QP + c]      = k0v;
            *(uint4*)&Kt[r * QP + c + 8]  = k1v;
            *(uint4*)&Rt[r * QP + c]      = r0v;
            *(uint4*)&Rt[r * QP + c + 8]  = r1v;
            *(uint4*)&VtT[r * QP + c]     = v0v;
            *(uint4*)&VtT[r * QP + c + 8] = v1v;
        }
        __syncthreads();

        const v4f z = (v4f){0.f, 0.f, 0.f, 0.f};
        // Content scores + pos chunk
        v4f sc[4];
        #pragma unroll
        for (int t = 0; t < 4; ++t) {
            v8s bk0 = *(v8s*)&Kt[(t * 16 + l15) * QP + quad * 8];
            v8s bk1 = *(v8s*)&Kt[(t * 16 + l15) * QP + 32 + quad * 8];
            sc[t] = __builtin_amdgcn_mfma_f32_16x16x32_bf16(aqc0, bk0, z, 0, 0, 0);
            sc[t] = __builtin_amdgcn_mfma_f32_16x16x32_bf16(aqc1, bk1, sc[t], 0, 0, 0);
        }
        const int lbase = j0 + c0;
        #pragma unroll
        for (int t = 0; t < 4; ++t) {
            v8s br0 = *(v8s*)&Rt[(t * 16 + l15) * QP + quad * 8];
            v8s br1 = *(v8s*)&Rt[(t * 16 + l15) * QP + 32 + quad * 8];
            v4f pp = __builtin_amdgcn_mfma_f32_16x16x32_bf16(aqp0, br0, z, 0, 0, 0);
            pp = __builtin_amdgcn_mfma_f32_16x16x32_bf16(aqp1, br1, pp, 0, 0, 0);
            #pragma unroll
            for (int v = 0; v < 4; ++v)
                ring[(w16 + quad * 4 + v) * RINGP + ((lbase + t * 16 + l15) & 127)] = f2bf(pp[v]);
        }

        // Scores -> exp -> Pt (wave-private rows; same-wave LDS dep in-order)
        #pragma unroll
        for (int t = 0; t < 4; ++t) {
            #pragma unroll
            for (int v = 0; v < 4; ++v) {
                const int irow = w16 + quad * 4 + v;
                const int l = (j0 + t * 16 + l15) + Ss - (i0 + irow);
                const float pos = bf2f(ring[irow * RINGP + (l & 127)]);
                const float p = __expf(sc[t][v] + pos);
                la[v] += p;
                Pt[irow * PTP + t * 16 + l15] = f2bf(p);
            }
        }

        // PV
        v8s pa0 = *(v8s*)&Pt[(w16 + l15) * PTP + quad * 8];
        v8s pa1 = *(v8s*)&Pt[(w16 + l15) * PTP + 32 + quad * 8];
        #pragma unroll
        for (int ht = 0; ht < 4; ++ht) {
            v8s bv0 = *(v8s*)&VtT[(ht * 16 + l15) * QP + quad * 8];
            v8s bv1 = *(v8s*)&VtT[(ht * 16 + l15) * QP + 32 + quad * 8];
            Oa[ht] = __builtin_amdgcn_mfma_f32_16x16x32_bf16(pa0, bv0, Oa[ht], 0, 0, 0);
            Oa[ht] = __builtin_amdgcn_mfma_f32_16x16x32_bf16(pa1, bv1, Oa[ht], 0, 0, 0);
        }
    }

    // ---- Epilogue: reduce row sums across quad, normalize, store ----
    #pragma unroll
    for (int v = 0; v < 4; ++v) {
        la[v] += __shfl_xor(la[v], 1);
        la[v] += __shfl_xor(la[v], 2);
        la[v] += __shfl_xor(la[v], 4);
        la[v] += __shfl_xor(la[v], 8);
        la[v] = 1.f / la[v];
    }
    #pragma unroll
    for (int ht = 0; ht < 4; ++ht) {
        #pragma unroll
        for (int v = 0; v < 4; ++v) {
            const int irow = w16 + quad * 4 + v;
            attn[(size_t)(b * Ss + i0 + irow) * NHh + n * 64 + ht * 16 + l15] =
                f2bf(Oa[ht][v] * la[v]);
        }
    }
}

// ---------------------------------------------------------------------------
// Fused residual-add + LayerNorm over E=1024; optional bf16 copy of output.
// ---------------------------------------------------------------------------
template<int W16>
__global__ __launch_bounds__(256) void add_ln_kernel(
    const float* __restrict__ a, const float* __restrict__ res,
    const float* __restrict__ g, const float* __restrict__ bet,
    float* __restrict__ out, us* __restrict__ out16)
{
    const int row = blockIdx.x;
    const int tid = threadIdx.x;
    const float* ar = a   + (size_t)row * Ee;
    const float* rr = res + (size_t)row * Ee;

    float vals[4];
    float lsum = 0.f, lsq = 0.f;
    #pragma unroll
    for (int it = 0; it < 4; ++it) {
        const int idx = tid + it * 256;
        const float vv = ar[idx] + rr[idx];
        vals[it] = vv;
        lsum += vv;
        lsq  = fmaf(vv, vv, lsq);
    }
    #pragma unroll
    for (int off = 32; off > 0; off >>= 1) {
        lsum += __shfl_down(lsum, off);
        lsq  += __shfl_down(lsq,  off);
    }
    __shared__ float w1[4], w2[4];
    if ((tid & 63) == 0) { w1[tid >> 6] = lsum; w2[tid >> 6] = lsq; }
    __syncthreads();
    const float sum  = w1[0] + w1[1] + w1[2] + w1[3];
    const float sq   = w2[0] + w2[1] + w2[2] + w2[3];
    const float mean = sum * (1.f / 1024.f);
    const float var  = sq * (1.f / 1024.f) - mean * mean;
    const float rstd = rsqrtf(var + 1e-12f);
    #pragma unroll
    for (int it = 0; it < 4; ++it) {
        const int idx = tid + it * 256;
        const float o = (vals[it] - mean) * rstd * g[idx] + bet[idx];
        out[(size_t)row * Ee + idx] = o;
        if (W16) out16[(size_t)row * Ee + idx] = f2bf(o);
    }
}

// ---------------------------------------------------------------------------
// Orchestration. Workspace layout (1 MB units), 90 MB total:
//   [ 0, 8)  x16      -> attn16 (ph3)  -> inner16 head (ph6)
//   [ 8,24)  rpe16    -> vT16 [8,16) (ph2.5), ao fp32 [16,24) (ph4)
//   [24,30)  Wqkv_t   [30,32) Wr_t   [32,34) Wo_t      (inner16 covers 0..32)
//   [34,42)  Wi_t     [42,50) Wout_t
//   [50,74)  qkv16    -> h16 [50,58) + hb fp32 [58,74) (ph5)
//   [74,90)  r16      -> out2 fp32 (ph7)
// ---------------------------------------------------------------------------
#define MB (1u << 20)

extern "C" void kernel_launch(void* const* d_in, const int* in_sizes, int n_in,
                              void* d_out, int out_size, void* d_ws, size_t ws_size,
                              hipStream_t stream)
{
    (void)in_sizes; (void)n_in; (void)out_size; (void)ws_size;

    const float* x    = (const float*)d_in[0];
    const float* cbf  = (const float*)d_in[1];
    const float* pbf  = (const float*)d_in[2];
    const float* rpe  = (const float*)d_in[3];
    const float* Wq   = (const float*)d_in[4];
    const float* Wk   = (const float*)d_in[5];
    const float* Wv   = (const float*)d_in[6];
    const float* Wr   = (const float*)d_in[7];
    const float* Wo   = (const float*)d_in[8];
    const float* ln1g = (const float*)d_in[9];
    const float* ln1b = (const float*)d_in[10];
    const float* Wi   = (const float*)d_in[11];
    const float* bi   = (const float*)d_in[12];
    const float* Wout = (const float*)d_in[13];
    const float* bout = (const float*)d_in[14];
    const float* ln2g = (const float*)d_in[15];
    const float* ln2b = (const float*)d_in[16];

    float* out = (float*)d_out;
    char*  ws  = (char*)d_ws;

    us* x16    = (us*)(ws + 0 * MB);
    us* rpe16  = (us*)(ws + 8 * MB);
    us* Wqkv_t = (us*)(ws + 24 * MB);           // [3072][1024]
    us* Wr_t   = (us*)(ws + 30 * MB);
    us* Wo_t   = (us*)(ws + 32 * MB);
    us* Wi_t   = (us*)(ws + 34 * MB);
    us* Wout_t = (us*)(ws + 42 * MB);
    us* qkv16  = (us*)(ws + 50 * MB);           // [BS][3072]
    us* r16    = (us*)(ws + 74 * MB);
    us* vT16   = (us*)(ws + 8 * MB);            // reuse rpe16 (after qkv_r gemm)
    us* attn16 = (us*)(ws + 0 * MB);            // reuse x16
    float* ao  = (float*)(ws + 16 * MB);        // [16,24)
    us* h16    = (us*)(ws + 50 * MB);           // reuse qkv16
    float* hb  = (float*)(ws + 58 * MB);        // reuse qkv16 tail
    us* inner16= (us*)(ws + 0 * MB);            // 0..32 MB
    float* out2= (float*)(ws + 74 * MB);        // reuse r16

    const dim3 blk(256);

    // Phase 1: converts + transposes (merged launches)
    cvt_x_rpe<<<dim3(12288), blk, 0, stream>>>(x, x16, rpe, rpe16);
    tr5<<<dim3(32, 32, 5), blk, 0, stream>>>(
        Wq, Wk, Wv, Wr, Wo,
        Wqkv_t, Wqkv_t + 1024 * 1024, Wqkv_t + 2048 * 1024, Wr_t, Wo_t);
    tr_ffn<<<dim3(128, 32, 2), blk, 0, stream>>>(Wi, Wi_t, Wout, Wout_t);

    // Phase 2: fused QKV + R projection (one 1280-block dispatch)
    gemm_qkv_r<<<dim3(1280), blk, 0, stream>>>(x16, Wqkv_t, qkv16, rpe16, Wr_t, r16);

    // Phase 2.5: V transpose (v cols of qkv) -> [B,N,H,S]
    transpose_v<<<dim3(16, 64), blk, 0, stream>>>(qkv16 + 2048, vT16, QKVLD);

    // Phase 3: MFMA flash attention
    attn_mfma<<<dim3(16, Nn, Bb), blk, 0, stream>>>(qkv16, vT16, r16, cbf, pbf, attn16);

    // Phase 4: output projection (fp32 out), 64-row tiles -> 512 blocks (2/CU)
    gemm_tile<2,0,0,0><<<dim3(8, 64), blk, 0, stream>>>(attn16, Wo_t, nullptr, ao, NHh, Ee);

    // Phase 5: h = LN1(ao + x), fp32 + bf16
    add_ln_kernel<1><<<dim3(BSs), blk, 0, stream>>>(ao, x, ln1g, ln1b, hb, h16);

    // Phase 6: FFN1 (bias+relu, bf16 out), 128-row tiles, 1024 blocks
    gemm_tile<4,1,1,1><<<dim3(32, 32), blk, 0, stream>>>(h16, Wi_t, bi, inner16, Ee, Ff);

    // Phase 7: FFN2 (bias, fp32 out), 64-row tiles -> 512 blocks (2+/CU)
    gemm_tile<2,0,1,0><<<dim3(8, 64), blk, 0, stream>>>(inner16, Wout_t, bout, out2, Ff, Ee);

    // Phase 8: out = LN2(out2 + h)
    add_ln_kernel<0><<<dim3(BSs), blk, 0, stream>>>(out2, hb, ln2g, ln2b, out, nullptr);
}

// Round 9
// 451.089 us; speedup vs baseline: 23.3539x; 1.0229x over previous
//
#include <hip/hip_runtime.h>
#include <math.h>

// Problem constants
#define Bb   4
#define Ss   1024
#define Ee   1024
#define Nn   16
#define Hh   64
#define Ff   4096
#define Rr   2048
#define NHh  1024   // N*H
#define BSs  4096   // B*S
#define QKVLD 3072  // fused qkv row stride

typedef short v8s __attribute__((ext_vector_type(8)));
typedef float v4f __attribute__((ext_vector_type(4)));
typedef unsigned short v4us __attribute__((ext_vector_type(4)));
typedef unsigned int u32;
typedef unsigned short us;

static __device__ inline us f2bf(float f) {
    u32 u = __builtin_bit_cast(u32, f);
    u += 0x7fffu + ((u >> 16) & 1u);   // RNE
    return (us)(u >> 16);
}
static __device__ inline float bf2f(us h) {
    u32 u = ((u32)h) << 16;
    return __builtin_bit_cast(float, u);
}
static __device__ inline void g2lds16(const void* g, void* l) {
    __builtin_amdgcn_global_load_lds(
        (const __attribute__((address_space(1))) u32*)g,
        (__attribute__((address_space(3))) u32*)l, 16, 0, 0);
}

// ---------------------------------------------------------------------------
// Transpose + cvt core: in [K][N] fp32 -> out [N][K] bf16, 32x32 tile.
// ---------------------------------------------------------------------------
static __device__ __forceinline__ void tr_core(
    float (*t)[33],
    const float* __restrict__ in, us* __restrict__ out,
    int K, int N, int i0, int j0)
{
    const int r  = threadIdx.x >> 3;
    const int c4 = (threadIdx.x & 7) * 4;
    const float4 v = *reinterpret_cast<const float4*>(in + (size_t)(i0 + r) * N + j0 + c4);
    t[r][c4 + 0] = v.x; t[r][c4 + 1] = v.y; t[r][c4 + 2] = v.z; t[r][c4 + 3] = v.w;
    __syncthreads();
    ushort4 o;
    o.x = f2bf(t[c4 + 0][r]); o.y = f2bf(t[c4 + 1][r]);
    o.z = f2bf(t[c4 + 2][r]); o.w = f2bf(t[c4 + 3][r]);
    *reinterpret_cast<ushort4*>(out + (size_t)(j0 + r) * K + i0 + c4) = o;
}

// ---------------------------------------------------------------------------
// One merged prep kernel: x/rpe cvt (blocks [0,12288)), 5 square weight
// transposes ([12288,17408)), Wi/Wout transposes ([17408,25600)).
// ---------------------------------------------------------------------------
__global__ __launch_bounds__(256) void prep_all(
    const float* __restrict__ x, us* __restrict__ x16,
    const float* __restrict__ rpe, us* __restrict__ rpe16,
    const float* __restrict__ Wq, const float* __restrict__ Wk,
    const float* __restrict__ Wv, const float* __restrict__ Wr,
    const float* __restrict__ Wo,
    us* __restrict__ Wqkv_t, us* __restrict__ Wr_t, us* __restrict__ Wo_t,
    const float* __restrict__ Wi, us* __restrict__ Wi_t,
    const float* __restrict__ Wout, us* __restrict__ Wout_t)
{
    __shared__ float t[32][33];
    const int bid = blockIdx.x;
    if (bid < 12288) {
        const float* in; us* out; size_t base;
        if (bid < 4096) { in = x; out = x16; base = (size_t)bid; }
        else { in = rpe; out = rpe16; base = (size_t)(bid - 4096); }
        const size_t i = (base * 256 + threadIdx.x) * 4;
        const float4 v = *reinterpret_cast<const float4*>(in + i);
        ushort4 o;
        o.x = f2bf(v.x); o.y = f2bf(v.y); o.z = f2bf(v.z); o.w = f2bf(v.w);
        *reinterpret_cast<ushort4*>(out + i) = o;
    } else if (bid < 17408) {
        const int local = bid - 12288;
        const int z = local >> 10;
        const int rem = local & 1023;
        const int i0 = (rem >> 5) * 32;
        const int j0 = (rem & 31) * 32;
        const float* in; us* out;
        switch (z) {
            case 0: in = Wq; out = Wqkv_t; break;
            case 1: in = Wk; out = Wqkv_t + 1024 * 1024; break;
            case 2: in = Wv; out = Wqkv_t + 2048 * 1024; break;
            case 3: in = Wr; out = Wr_t; break;
            default: in = Wo; out = Wo_t; break;
        }
        tr_core(t, in, out, 1024, 1024, i0, j0);
    } else {
        const int local = bid - 17408;
        if (local < 4096) {
            const int xb = local & 127, yb = local >> 7;
            tr_core(t, Wi, Wi_t, 1024, 4096, yb * 32, xb * 32);
        } else {
            const int l2 = local - 4096;
            const int xb = l2 & 127, yb = l2 >> 7;
            tr_core(t, Wout, Wout_t, 4096, 1024, xb * 32, yb * 32);
        }
    }
}

// ---------------------------------------------------------------------------
// Per-(b,n) transpose of V: v16 (stride ld) [B,S,*] -> vT16 [B,N,H,S] bf16.
// ---------------------------------------------------------------------------
__global__ __launch_bounds__(256) void transpose_v(
    const us* __restrict__ v16, us* __restrict__ vT16, int ld)
{
    __shared__ us T[64][72];
    const int s0 = blockIdx.x * 64;
    const int bn = blockIdx.y;          // b*16 + n
    const int b  = bn >> 4, n = bn & 15;
    const int t  = threadIdx.x;
    {
        const int r = t >> 2, c = (t & 3) * 16;
        const uint4* src = (const uint4*)(v16 + (size_t)(b * Ss + s0 + r) * ld + n * 64 + c);
        *(uint4*)&T[r][c]     = src[0];
        *(uint4*)&T[r][c + 8] = src[1];
    }
    __syncthreads();
    {
        const int h = t >> 2, c2 = (t & 3) * 16;
        us tmp[16];
        #pragma unroll
        for (int u = 0; u < 16; ++u) tmp[u] = T[c2 + u][h];
        us* dst = vT16 + (size_t)(bn * 64 + h) * Ss + s0 + c2;
        *(uint4*)dst       = *(uint4*)tmp;
        *(uint4*)(dst + 8) = *(uint4*)(tmp + 8);
    }
}

// ---------------------------------------------------------------------------
// bf16 MFMA GEMM body: C = A[M,K] @ B^T (B as [N][K]).
// Tile: (MT*32) x 128, BK=64, 4 waves 2x2; XOR-swizzled LDS (see R6/R7).
// ---------------------------------------------------------------------------
template<int MT, int OUT_BF16, int BIAS, int RELU>
static __device__ __forceinline__ void gemm_body(
    us* __restrict__ Asm, us* __restrict__ Bsm,
    const us* __restrict__ A, const us* __restrict__ B,
    const float* __restrict__ bias, void* __restrict__ Cv,
    int K, int ldC, int row0, int col0)
{
    const int tid  = threadIdx.x;
    const int lane = tid & 63;
    const int wave = tid >> 6;
    const int wr   = wave >> 1, wc = wave & 1;
    const int lrow = lane & 15;
    const int lq   = lane >> 4;
    const int h3   = lrow & 7;

    v4f acc[MT][4];
    #pragma unroll
    for (int mt = 0; mt < MT; ++mt)
        #pragma unroll
        for (int nt = 0; nt < 4; ++nt)
            acc[mt][nt] = (v4f){0.f, 0.f, 0.f, 0.f};

    for (int k0 = 0; k0 < K; k0 += 64) {
        #pragma unroll
        for (int u = 0; u < MT; ++u) {
            const int slot = u * 256 + tid;
            const int sr = slot >> 3;
            const int sc = ((slot & 7) ^ (sr & 7)) * 8;
            g2lds16(A + (size_t)(row0 + sr) * K + k0 + sc, &Asm[slot * 8]);
        }
        #pragma unroll
        for (int u = 0; u < 4; ++u) {
            const int slot = u * 256 + tid;
            const int sr = slot >> 3;
            const int sc = ((slot & 7) ^ (sr & 7)) * 8;
            g2lds16(B + (size_t)(col0 + sr) * K + k0 + sc, &Bsm[slot * 8]);
        }
        __syncthreads();

        #pragma unroll
        for (int t = 0; t < 2; ++t) {
            const int cc = ((lq + 4 * t) ^ h3) * 8;
            v8s af[MT], bf[4];
            #pragma unroll
            for (int mt = 0; mt < MT; ++mt)
                af[mt] = *reinterpret_cast<const v8s*>(
                    &Asm[(wr * (MT * 16) + mt * 16 + lrow) * 64 + cc]);
            #pragma unroll
            for (int nt = 0; nt < 4; ++nt)
                bf[nt] = *reinterpret_cast<const v8s*>(
                    &Bsm[(wc * 64 + nt * 16 + lrow) * 64 + cc]);
            #pragma unroll
            for (int mt = 0; mt < MT; ++mt)
                #pragma unroll
                for (int nt = 0; nt < 4; ++nt)
                    acc[mt][nt] = __builtin_amdgcn_mfma_f32_16x16x32_bf16(
                        af[mt], bf[nt], acc[mt][nt], 0, 0, 0);
        }
        __syncthreads();
    }

    #pragma unroll
    for (int nt = 0; nt < 4; ++nt) {
        const int col = col0 + wc * 64 + nt * 16 + lrow;
        const float bv = BIAS ? bias[col] : 0.f;
        #pragma unroll
        for (int mt = 0; mt < MT; ++mt) {
            #pragma unroll
            for (int v = 0; v < 4; ++v) {
                const int row = row0 + wr * (MT * 16) + mt * 16 + lq * 4 + v;
                float val = acc[mt][nt][v] + bv;
                if (RELU) val = fmaxf(val, 0.f);
                if (OUT_BF16)
                    ((us*)Cv)[(size_t)row * ldC + col] = f2bf(val);
                else
                    ((float*)Cv)[(size_t)row * ldC + col] = val;
            }
        }
    }
}

template<int MT, int OUT_BF16, int BIAS, int RELU>
__global__ __launch_bounds__(256) void gemm_tile(
    const us* __restrict__ A, const us* __restrict__ B,
    const float* __restrict__ bias, void* __restrict__ Cv,
    int K, int ldC)
{
    __shared__ us Asm[MT * 32 * 64];
    __shared__ us Bsm[128 * 64];
    gemm_body<MT, OUT_BF16, BIAS, RELU>(Asm, Bsm, A, B, bias, Cv, K, ldC,
                                        blockIdx.y * (MT * 32), blockIdx.x * 128);
}

// Fused QKV (768 blocks) + R (512 blocks) projection in one 1280-block launch.
__global__ __launch_bounds__(256) void gemm_qkv_r(
    const us* __restrict__ x16, const us* __restrict__ Wqkv,
    us* __restrict__ qkv, const us* __restrict__ rpe16,
    const us* __restrict__ Wr, us* __restrict__ rout)
{
    __shared__ us Asm[128 * 64];
    __shared__ us Bsm[128 * 64];
    const int bid = blockIdx.x;
    if (bid < 768) {
        gemm_body<4,1,0,0>(Asm, Bsm, x16, Wqkv, nullptr, qkv, Ee, QKVLD,
                           (bid / 24) * 128, (bid % 24) * 128);
    } else {
        const int b2 = bid - 768;
        gemm_body<4,1,0,0>(Asm, Bsm, rpe16, Wr, nullptr, rout, Ee, NHh,
                           (b2 / 8) * 128, (b2 % 8) * 128);
    }
}

// ---------------------------------------------------------------------------
// MFMA flash attention with rel-shift ring buffer (see R3-R7 notes).
// R8: grid = (bn, i-tile) so all 16 i-tiles of one (b,n) land on the same XCD
// (flat = bn + 64*i -> XCD = bn mod 8): K/R/V fetched once per XCD.
// R8: ring is skewed column-major: entry pos[irow][l] stored at
// ring[(l - Ss + i0 + irow) & 127][irow] == ring[j & 127][irow]; score reads
// become 4x ds_read_b64 (rows v=0..3 contiguous), replacing 16 scalar reads.
// ---------------------------------------------------------------------------
#define QP 72      // pitch for qc/qp/Kt/Rt/VtT
#define PTP 68     // Pt pitch
#define RP 68      // ring cm row pitch (64 rows + 4 pad; even*4 for b64 align)

__global__ __launch_bounds__(256) void attn_mfma(
    const us* __restrict__ qkv, const us* __restrict__ vT16,
    const us* __restrict__ r16,
    const float* __restrict__ cb, const float* __restrict__ pb,
    us* __restrict__ attn)
{
    __shared__ __align__(16) char smem[53760];
    us* qcS  = (us*)smem;              // prologue only
    us* qpS  = (us*)(smem + 9216);     // prologue only
    us* Kt   = (us*)smem;              // main loop (overlays qcS)
    us* Rt   = (us*)(smem + 9216);     // main loop (overlays qpS)
    us* VtT  = (us*)(smem + 18432);
    us* ring = (us*)(smem + 27648);    // cm: 128 cols x 68-row pitch = 17408 B
    us* Pt   = (us*)(smem + 45056);    // 64 x 68 bf16 = 8704 B

    const int bn = blockIdx.x;         // b*16 + n  (XCD = bn & 7)
    const int b  = bn >> 4;
    const int n  = bn & 15;
    const int i0 = blockIdx.y * 64;
    const int tid  = threadIdx.x;
    const int lane = tid & 63;
    const int w    = tid >> 6;
    const int quad = lane >> 4;
    const int l15  = lane & 15;
    const int w16  = w * 16;

    // ---- Prologue: stage qc = (q+cb)*0.125, qp = (q+pb)*0.125 (bf16) ----
    {
        const int r = tid >> 2, c = (tid & 3) * 16;
        const uint4* src = (const uint4*)(qkv + (size_t)(b * Ss + i0 + r) * QKVLD + n * 64 + c);
        uint4 qa = src[0], qb = src[1];
        us qs[16];
        *(uint4*)qs       = qa;
        *(uint4*)(qs + 8) = qb;
        const float* cbp = cb + n * 64 + c;
        const float* pbp = pb + n * 64 + c;
        us oc[16], op[16];
        #pragma unroll
        for (int u = 0; u < 16; ++u) {
            const float qf = bf2f(qs[u]);
            oc[u] = f2bf((qf + cbp[u]) * 0.125f);
            op[u] = f2bf((qf + pbp[u]) * 0.125f);
        }
        *(uint4*)&qcS[r * QP + c]     = *(uint4*)oc;
        *(uint4*)&qcS[r * QP + c + 8] = *(uint4*)(oc + 8);
        *(uint4*)&qpS[r * QP + c]     = *(uint4*)op;
        *(uint4*)&qpS[r * QP + c + 8] = *(uint4*)(op + 8);
    }
    __syncthreads();

    // A-fragments in registers (wave w owns queries [w16, w16+16))
    v8s aqc0 = *(v8s*)&qcS[(w16 + l15) * QP + quad * 8];
    v8s aqc1 = *(v8s*)&qcS[(w16 + l15) * QP + 32 + quad * 8];
    v8s aqp0 = *(v8s*)&qpS[(w16 + l15) * QP + quad * 8];
    v8s aqp1 = *(v8s*)&qpS[(w16 + l15) * QP + 32 + quad * 8];
    __syncthreads();   // all reads done before Kt/Rt overlay

    const int c0 = Ss - i0;   // l at j-i diag base

    // ---- Bootstrap: pos chunk l in [c0-64, c0) -> ring cols j in [irow-i0-64, irow-i0) ----
    {
        const int r = tid >> 2, c = (tid & 3) * 16;
        const uint4* src = (const uint4*)(r16 + (size_t)(b * Rr + (c0 - 64) + r) * NHh + n * 64 + c);
        *(uint4*)&Rt[r * QP + c]     = src[0];
        *(uint4*)&Rt[r * QP + c + 8] = src[1];
        __syncthreads();
        const v4f z = (v4f){0.f, 0.f, 0.f, 0.f};
        #pragma unroll
        for (int t = 0; t < 4; ++t) {
            v8s br0 = *(v8s*)&Rt[(t * 16 + l15) * QP + quad * 8];
            v8s br1 = *(v8s*)&Rt[(t * 16 + l15) * QP + 32 + quad * 8];
            v4f pp = __builtin_amdgcn_mfma_f32_16x16x32_bf16(aqp0, br0, z, 0, 0, 0);
            pp = __builtin_amdgcn_mfma_f32_16x16x32_bf16(aqp1, br1, pp, 0, 0, 0);
            const int colbase = t * 16 + l15 - 64;   // j = colbase + irow
            #pragma unroll
            for (int v = 0; v < 4; ++v) {
                const int irow = w16 + quad * 4 + v;
                ring[((colbase + irow) & 127) * RP + irow] = f2bf(pp[v]);
            }
        }
    }

    v4f Oa[4];
    #pragma unroll
    for (int t = 0; t < 4; ++t) Oa[t] = (v4f){0.f, 0.f, 0.f, 0.f};
    float la[4] = {0.f, 0.f, 0.f, 0.f};

    // ---- Main flash loop over key tiles ----
    for (int j0 = 0; j0 < Ss; j0 += 64) {
        __syncthreads();   // prev iter LDS reads done
        {
            const int r = tid >> 2, c = (tid & 3) * 16;
            const uint4* sk = (const uint4*)(qkv + (size_t)(b * Ss + j0 + r) * QKVLD + NHh + n * 64 + c);
            const uint4* sr = (const uint4*)(r16 + (size_t)(b * Rr + (j0 + c0) + r) * NHh + n * 64 + c);
            const uint4* sv = (const uint4*)(vT16 + (size_t)(bn * 64 + r) * Ss + j0 + c);
            uint4 k0v = sk[0], k1v = sk[1];
            uint4 r0v = sr[0], r1v = sr[1];
            uint4 v0v = sv[0], v1v = sv[1];
            *(uint4*)&Kt[r * QP + c]      = k0v;
            *(uint4*)&Kt[r * QP + c + 8]  = k1v;
            *(uint4*)&Rt[r * QP + c]      = r0v;
            *(uint4*)&Rt[r * QP + c + 8]  = r1v;
            *(uint4*)&VtT[r * QP + c]     = v0v;
            *(uint4*)&VtT[r * QP + c + 8] = v1v;
        }
        __syncthreads();

        const v4f z = (v4f){0.f, 0.f, 0.f, 0.f};
        // Content scores
        v4f sc[4];
        #pragma unroll
        for (int t = 0; t < 4; ++t) {
            v8s bk0 = *(v8s*)&Kt[(t * 16 + l15) * QP + quad * 8];
            v8s bk1 = *(v8s*)&Kt[(t * 16 + l15) * QP + 32 + quad * 8];
            sc[t] = __builtin_amdgcn_mfma_f32_16x16x32_bf16(aqc0, bk0, z, 0, 0, 0);
            sc[t] = __builtin_amdgcn_mfma_f32_16x16x32_bf16(aqc1, bk1, sc[t], 0, 0, 0);
        }
        // Pos chunk -> ring (skewed cm: col = j & 127, row = irow)
        #pragma unroll
        for (int t = 0; t < 4; ++t) {
            v8s br0 = *(v8s*)&Rt[(t * 16 + l15) * QP + quad * 8];
            v8s br1 = *(v8s*)&Rt[(t * 16 + l15) * QP + 32 + quad * 8];
            v4f pp = __builtin_amdgcn_mfma_f32_16x16x32_bf16(aqp0, br0, z, 0, 0, 0);
            pp = __builtin_amdgcn_mfma_f32_16x16x32_bf16(aqp1, br1, pp, 0, 0, 0);
            const int colbase = j0 + t * 16 + l15;   // j = colbase + (irow - w16... ) no: j = colbase + irow - 0
            #pragma unroll
            for (int v = 0; v < 4; ++v) {
                const int irow = w16 + quad * 4 + v;
                ring[((colbase + irow) & 127) * RP + irow] = f2bf(pp[v]);
            }
        }

        // Scores -> exp -> Pt; pos gathered via one b64 per t (4 rows packed)
        #pragma unroll
        for (int t = 0; t < 4; ++t) {
            const v4us pr = *(const v4us*)&ring[((j0 + t * 16 + l15) & 127) * RP + w16 + quad * 4];
            #pragma unroll
            for (int v = 0; v < 4; ++v) {
                const int irow = w16 + quad * 4 + v;
                const float p = __expf(sc[t][v] + bf2f(pr[v]));
                la[v] += p;
                Pt[irow * PTP + t * 16 + l15] = f2bf(p);
            }
        }

        // PV
        v8s pa0 = *(v8s*)&Pt[(w16 + l15) * PTP + quad * 8];
        v8s pa1 = *(v8s*)&Pt[(w16 + l15) * PTP + 32 + quad * 8];
        #pragma unroll
        for (int ht = 0; ht < 4; ++ht) {
            v8s bv0 = *(v8s*)&VtT[(ht * 16 + l15) * QP + quad * 8];
            v8s bv1 = *(v8s*)&VtT[(ht * 16 + l15) * QP + 32 + quad * 8];
            Oa[ht] = __builtin_amdgcn_mfma_f32_16x16x32_bf16(pa0, bv0, Oa[ht], 0, 0, 0);
            Oa[ht] = __builtin_amdgcn_mfma_f32_16x16x32_bf16(pa1, bv1, Oa[ht], 0, 0, 0);
        }
    }

    // ---- Epilogue: reduce row sums across quad, normalize, store ----
    #pragma unroll
    for (int v = 0; v < 4; ++v) {
        la[v] += __shfl_xor(la[v], 1);
        la[v] += __shfl_xor(la[v], 2);
        la[v] += __shfl_xor(la[v], 4);
        la[v] += __shfl_xor(la[v], 8);
        la[v] = 1.f / la[v];
    }
    #pragma unroll
    for (int ht = 0; ht < 4; ++ht) {
        #pragma unroll
        for (int v = 0; v < 4; ++v) {
            const int irow = w16 + quad * 4 + v;
            attn[(size_t)(b * Ss + i0 + irow) * NHh + n * 64 + ht * 16 + l15] =
                f2bf(Oa[ht][v] * la[v]);
        }
    }
}

// ---------------------------------------------------------------------------
// Fused residual-add + LayerNorm over E=1024; optional bf16 copy of output.
// ---------------------------------------------------------------------------
template<int W16>
__global__ __launch_bounds__(256) void add_ln_kernel(
    const float* __restrict__ a, const float* __restrict__ res,
    const float* __restrict__ g, const float* __restrict__ bet,
    float* __restrict__ out, us* __restrict__ out16)
{
    const int row = blockIdx.x;
    const int tid = threadIdx.x;
    const float* ar = a   + (size_t)row * Ee;
    const float* rr = res + (size_t)row * Ee;

    float vals[4];
    float lsum = 0.f, lsq = 0.f;
    #pragma unroll
    for (int it = 0; it < 4; ++it) {
        const int idx = tid + it * 256;
        const float vv = ar[idx] + rr[idx];
        vals[it] = vv;
        lsum += vv;
        lsq  = fmaf(vv, vv, lsq);
    }
    #pragma unroll
    for (int off = 32; off > 0; off >>= 1) {
        lsum += __shfl_down(lsum, off);
        lsq  += __shfl_down(lsq,  off);
    }
    __shared__ float w1[4], w2[4];
    if ((tid & 63) == 0) { w1[tid >> 6] = lsum; w2[tid >> 6] = lsq; }
    __syncthreads();
    const float sum  = w1[0] + w1[1] + w1[2] + w1[3];
    const float sq   = w2[0] + w2[1] + w2[2] + w2[3];
    const float mean = sum * (1.f / 1024.f);
    const float var  = sq * (1.f / 1024.f) - mean * mean;
    const float rstd = rsqrtf(var + 1e-12f);
    #pragma unroll
    for (int it = 0; it < 4; ++it) {
        const int idx = tid + it * 256;
        const float o = (vals[it] - mean) * rstd * g[idx] + bet[idx];
        out[(size_t)row * Ee + idx] = o;
        if (W16) out16[(size_t)row * Ee + idx] = f2bf(o);
    }
}

// ---------------------------------------------------------------------------
// Orchestration. Workspace layout (1 MB units), 90 MB total:
//   [ 0, 8)  x16      -> attn16 (ph3)  -> inner16 head (ph6)
//   [ 8,24)  rpe16    -> vT16 [8,16) (ph2.5), ao fp32 [16,24) (ph4)
//   [24,30)  Wqkv_t   [30,32) Wr_t   [32,34) Wo_t      (inner16 covers 0..32)
//   [34,42)  Wi_t     [42,50) Wout_t
//   [50,74)  qkv16    -> h16 [50,58) + hb fp32 [58,74) (ph5)
//   [74,90)  r16      -> out2 fp32 (ph7)
// ---------------------------------------------------------------------------
#define MB (1u << 20)

extern "C" void kernel_launch(void* const* d_in, const int* in_sizes, int n_in,
                              void* d_out, int out_size, void* d_ws, size_t ws_size,
                              hipStream_t stream)
{
    (void)in_sizes; (void)n_in; (void)out_size; (void)ws_size;

    const float* x    = (const float*)d_in[0];
    const float* cbf  = (const float*)d_in[1];
    const float* pbf  = (const float*)d_in[2];
    const float* rpe  = (const float*)d_in[3];
    const float* Wq   = (const float*)d_in[4];
    const float* Wk   = (const float*)d_in[5];
    const float* Wv   = (const float*)d_in[6];
    const float* Wr   = (const float*)d_in[7];
    const float* Wo   = (const float*)d_in[8];
    const float* ln1g = (const float*)d_in[9];
    const float* ln1b = (const float*)d_in[10];
    const float* Wi   = (const float*)d_in[11];
    const float* bi   = (const float*)d_in[12];
    const float* Wout = (const float*)d_in[13];
    const float* bout = (const float*)d_in[14];
    const float* ln2g = (const float*)d_in[15];
    const float* ln2b = (const float*)d_in[16];

    float* out = (float*)d_out;
    char*  ws  = (char*)d_ws;

    us* x16    = (us*)(ws + 0 * MB);
    us* rpe16  = (us*)(ws + 8 * MB);
    us* Wqkv_t = (us*)(ws + 24 * MB);           // [3072][1024]
    us* Wr_t   = (us*)(ws + 30 * MB);
    us* Wo_t   = (us*)(ws + 32 * MB);
    us* Wi_t   = (us*)(ws + 34 * MB);
    us* Wout_t = (us*)(ws + 42 * MB);
    us* qkv16  = (us*)(ws + 50 * MB);           // [BS][3072]
    us* r16    = (us*)(ws + 74 * MB);
    us* vT16   = (us*)(ws + 8 * MB);            // reuse rpe16 (after qkv_r gemm)
    us* attn16 = (us*)(ws + 0 * MB);            // reuse x16
    float* ao  = (float*)(ws + 16 * MB);        // [16,24)
    us* h16    = (us*)(ws + 50 * MB);           // reuse qkv16
    float* hb  = (float*)(ws + 58 * MB);        // reuse qkv16 tail
    us* inner16= (us*)(ws + 0 * MB);            // 0..32 MB
    float* out2= (float*)(ws + 74 * MB);        // reuse r16

    const dim3 blk(256);

    // Phase 1: all converts + transposes, one dispatch
    prep_all<<<dim3(25600), blk, 0, stream>>>(
        x, x16, rpe, rpe16, Wq, Wk, Wv, Wr, Wo,
        Wqkv_t, Wr_t, Wo_t, Wi, Wi_t, Wout, Wout_t);

    // Phase 2: fused QKV + R projection (one 1280-block dispatch)
    gemm_qkv_r<<<dim3(1280), blk, 0, stream>>>(x16, Wqkv_t, qkv16, rpe16, Wr_t, r16);

    // Phase 2.5: V transpose (v cols of qkv) -> [B,N,H,S]
    transpose_v<<<dim3(16, 64), blk, 0, stream>>>(qkv16 + 2048, vT16, QKVLD);

    // Phase 3: MFMA flash attention; grid (bn, i) for XCD-local K/R/V reuse
    attn_mfma<<<dim3(64, 16), blk, 0, stream>>>(qkv16, vT16, r16, cbf, pbf, attn16);

    // Phase 4: output projection (fp32 out), 64-row tiles -> 512 blocks (2/CU)
    gemm_tile<2,0,0,0><<<dim3(8, 64), blk, 0, stream>>>(attn16, Wo_t, nullptr, ao, NHh, Ee);

    // Phase 5: h = LN1(ao + x), fp32 + bf16
    add_ln_kernel<1><<<dim3(BSs), blk, 0, stream>>>(ao, x, ln1g, ln1b, hb, h16);

    // Phase 6: FFN1 (bias+relu, bf16 out), 128-row tiles, 1024 blocks
    gemm_tile<4,1,1,1><<<dim3(32, 32), blk, 0, stream>>>(h16, Wi_t, bi, inner16, Ee, Ff);

    // Phase 7: FFN2 (bias, fp32 out), 64-row tiles -> 512 blocks (2+/CU)
    gemm_tile<2,0,1,0><<<dim3(8, 64), blk, 0, stream>>>(inner16, Wout_t, bout, out2, Ff, Ee);

    // Phase 8: out = LN2(out2 + h)
    add_ln_kernel<0><<<dim3(BSs), blk, 0, stream>>>(out2, hb, ln2g, ln2b, out, nullptr);
}